// Round 7
// baseline (409.116 us; speedup 1.0000x reference)
//
#include <hip/hip_runtime.h>
#include <hip/hip_bf16.h>
#include <stdint.h>

// ImprovedLatticeRNNCell fused bf16-MFMA implementation, round 7.
// GEMM: 256x256 tile, BK=64, 512 thr (8 waves 2Mx4N), unified 128KiB LDS
// double-buffer, R6-proven vmcnt(8) pipeline, 2 sub-phases per K-tile
// (register-pressure control), setprio around MFMA, swizzled C epilogue.

#define NB 16384
#define NHEADS 4

typedef __attribute__((ext_vector_type(8))) __bf16 bf16x8;
typedef __attribute__((ext_vector_type(4))) float f32x4;
typedef __attribute__((ext_vector_type(8))) unsigned short u16x8;

__device__ __forceinline__ unsigned short f2bf(float f) {
  union { float f; unsigned int u; } v; v.f = f;
  unsigned int u = v.u;
  unsigned int r = (u + 0x7fffu + ((u >> 16) & 1u)) >> 16;
  return (unsigned short)r;
}
__device__ __forceinline__ float bf2f(unsigned short h) {
  union { unsigned int u; float f; } v; v.u = ((unsigned int)h) << 16;
  return v.f;
}
__device__ __forceinline__ float sigmoidf_(float x) {
  return 1.0f / (1.0f + __expf(-x));
}

// ---------------- merged f32 -> bf16 conversion (9 jobs, 1 launch) ----------
#define J0 (512 * 128 / 8)    // W_in -> wComb head
#define J1 (1536 * 128 / 8)   // gru_w_ih -> wComb tail
#define J2 (1536 * 512 / 8)   // attn_in_w
#define J3 (512 * 512 / 8)    // attn_out_w
#define J4 (512 * 1536 / 8)   // W_gate
#define J5 (1536 * 512 / 8)   // gru_w_hh
#define J6 (NB * 128 / 8)     // x
#define J7 (NB * 512 / 8)     // hl
#define J8 (NB * 512 / 8)     // hu
#define C1 (J0)
#define C2 (C1 + J1)
#define C3 (C2 + J2)
#define C4 (C3 + J3)
#define C5 (C4 + J4)
#define C6 (C5 + J5)
#define C7 (C6 + J6)
#define C8 (C7 + J7)
#define CT (C8 + J8)

struct CvtJobs {
  const float* src[9];
  unsigned short* dst[9];
};

__global__ void cvt_multi(CvtJobs j) {
  int g = blockIdx.x * blockDim.x + threadIdx.x;
  if (g >= CT) return;
  int k, base;
  if (g < C4) {
    if (g < C2) {
      if (g < C1) { k = 0; base = 0; } else { k = 1; base = C1; }
    } else {
      if (g < C3) { k = 2; base = C2; } else { k = 3; base = C3; }
    }
  } else {
    if (g < C6) {
      if (g < C5) { k = 4; base = C4; } else { k = 5; base = C5; }
    } else {
      if (g < C7) { k = 6; base = C6; }
      else if (g < C8) { k = 7; base = C7; }
      else { k = 8; base = C8; }
    }
  }
  int local = g - base;
  const float4* s = (const float4*)j.src[k] + (size_t)local * 2;
  float4 a = s[0], b = s[1];
  u16x8 o;
  o[0] = f2bf(a.x); o[1] = f2bf(a.y); o[2] = f2bf(a.z); o[3] = f2bf(a.w);
  o[4] = f2bf(b.x); o[5] = f2bf(b.y); o[6] = f2bf(b.z); o[7] = f2bf(b.w);
  *((u16x8*)j.dst[k] + local) = o;
}

// pack hidden_prev f32 [B,512] -> bf16 into gate_in [B,1536] cols 0..511
__global__ void pack_hp(const float* __restrict__ hp,
                        unsigned short* __restrict__ gate_in) {
  int t = blockIdx.x * blockDim.x + threadIdx.x;  // B*64 threads
  int b = t >> 6;
  int j = (t & 63) * 8;
  const float4* s = (const float4*)(hp + (size_t)b * 512 + j);
  float4 a = s[0], c = s[1];
  u16x8 o;
  o[0] = f2bf(a.x); o[1] = f2bf(a.y); o[2] = f2bf(a.z); o[3] = f2bf(a.w);
  o[4] = f2bf(c.x); o[5] = f2bf(c.y); o[6] = f2bf(c.z); o[7] = f2bf(c.w);
  *(u16x8*)(gate_in + (size_t)b * 1536 + j) = o;
}

// ---------------- GEMM: C[M,N] = A[M,K](bf16) * W[N,K]^T(bf16) + bias ----------------
__device__ __forceinline__ void gl_lds16(const unsigned short* g, unsigned short* l) {
  __builtin_amdgcn_global_load_lds(
      (const __attribute__((address_space(1))) void*)g,
      (__attribute__((address_space(3))) void*)l, 16, 0, 0);
}

// EPI 0: outb = bf16(acc+bias)   (swizzled LDS-staged coalesced store)
// EPI 1: gate epilogue (sigmoid, enhanced blend) -> outf(f32) + outb(bf16)
// EPI 2: router: global col<512 -> outb (ldob, bias), else outb2 (ldob2, bias2)
template <int EPI>
__global__ __launch_bounds__(512, 2) void gemm_bt(
    const unsigned short* __restrict__ A, int lda,
    const unsigned short* __restrict__ W, int ldw,
    const float* __restrict__ bias, const float* __restrict__ bias2,
    int K, int ntx,
    unsigned short* __restrict__ outb, int ldob,
    unsigned short* __restrict__ outb2, int ldob2,
    float* __restrict__ outf,
    const float* __restrict__ hp,
    const unsigned short* __restrict__ scb) {
  __shared__ unsigned short lds[65536];  // 128 KiB: A dbuf | W dbuf; C-stage reuse
  unsigned short* Asb = lds;             // [2][16384]
  unsigned short* Wsb = lds + 32768;     // [2][16384]
  const int tid = threadIdx.x;
  const int lane = tid & 63;
  const int wave = tid >> 6;  // 0..7

  // XCD-aware bijective swizzle (gridDim.x always a multiple of 8 here)
  const int nwg = gridDim.x;
  const int cpx = nwg >> 3;
  const int bid = blockIdx.x;
  const int id = (bid & 7) * cpx + (bid >> 3);
  const int bx = id % ntx;
  const int by = id / ntx;

  const int m0 = by * 256;
  const int n0 = bx * 256;
  const int wm = (wave >> 2) * 128;  // 0 or 128
  const int wn = (wave & 3) * 64;    // 0,64,128,192

  f32x4 acc[8][4] = {};

  // staging: thread covers rows srow+64i, 16B slot sslot (inverse-swizzled).
  const int srow = tid >> 3;                 // 0..63
  const int sslot = (tid & 7) ^ (srow & 7);  // source slot
  const unsigned short* Ag = A + (size_t)(m0 + srow) * lda + sslot * 8;
  const unsigned short* Wg = W + (size_t)(n0 + srow) * ldw + sslot * 8;
  unsigned short* Asd = Asb + tid * 8;
  unsigned short* Wsd = Wsb + tid * 8;

  auto stage = [&](int buf, int k0) {
#pragma unroll
    for (int i = 0; i < 4; ++i)
      gl_lds16(Ag + (size_t)(i * 64) * lda + k0, Asd + buf * 16384 + i * 4096);
#pragma unroll
    for (int i = 0; i < 4; ++i)
      gl_lds16(Wg + (size_t)(i * 64) * ldw + k0, Wsd + buf * 16384 + i * 4096);
  };

  stage(0, 0);
  int cur = 0;
  const int lrow = lane & 15;
  const int kq = (lane >> 4) * 8;  // shorts
  const int sw = (lrow & 7) << 3;  // read-side swizzle (shorts)

  for (int k0 = 0; k0 < K; k0 += 64) {
    if (k0 + 64 < K) {
      stage(cur ^ 1, k0 + 64);
      // 8 loads/stage: wait for the 8 oldest (current buffer), keep 8 in flight
      asm volatile("s_waitcnt vmcnt(8)" ::: "memory");
    } else {
      asm volatile("s_waitcnt vmcnt(0)" ::: "memory");
    }
    __builtin_amdgcn_s_barrier();
    const unsigned short* Ab = Asb + cur * 16384;
    const unsigned short* Wb = Wsb + cur * 16384;

    bf16x8 wfr[4][2], afr[4][2];
#pragma unroll
    for (int n = 0; n < 4; ++n)
#pragma unroll
      for (int kk = 0; kk < 2; ++kk)
        wfr[n][kk] = *(const bf16x8*)&Wb[(wn + n * 16 + lrow) * 64 + ((kk * 32 + kq) ^ sw)];
#pragma unroll
    for (int m = 0; m < 4; ++m)
#pragma unroll
      for (int kk = 0; kk < 2; ++kk)
        afr[m][kk] = *(const bf16x8*)&Ab[(wm + m * 16 + lrow) * 64 + ((kk * 32 + kq) ^ sw)];
    __builtin_amdgcn_s_setprio(1);
#pragma unroll
    for (int m = 0; m < 4; ++m)
#pragma unroll
      for (int n = 0; n < 4; ++n)
#pragma unroll
        for (int kk = 0; kk < 2; ++kk)
          acc[m][n] = __builtin_amdgcn_mfma_f32_16x16x32_bf16(afr[m][kk], wfr[n][kk],
                                                              acc[m][n], 0, 0, 0);
    __builtin_amdgcn_s_setprio(0);
    __builtin_amdgcn_sched_barrier(0);
    // sub-phase 1: reload A frags for rows wm+64..wm+127
#pragma unroll
    for (int m = 0; m < 4; ++m)
#pragma unroll
      for (int kk = 0; kk < 2; ++kk)
        afr[m][kk] = *(const bf16x8*)&Ab[(wm + 64 + m * 16 + lrow) * 64 + ((kk * 32 + kq) ^ sw)];
    __builtin_amdgcn_s_setprio(1);
#pragma unroll
    for (int m = 0; m < 4; ++m)
#pragma unroll
      for (int n = 0; n < 4; ++n)
#pragma unroll
        for (int kk = 0; kk < 2; ++kk)
          acc[m + 4][n] = __builtin_amdgcn_mfma_f32_16x16x32_bf16(afr[m][kk], wfr[n][kk],
                                                                  acc[m + 4][n], 0, 0, 0);
    __builtin_amdgcn_s_setprio(0);
    __builtin_amdgcn_s_barrier();
    cur ^= 1;
  }

  if constexpr (EPI == 1) {
    // gate epilogue: g = sigmoid(v); enhanced = hp + g*sc  (direct stores)
    const int r0 = m0 + wm + ((lane >> 4) << 2);
    const int c0 = n0 + wn + lrow;
#pragma unroll
    for (int n = 0; n < 4; ++n) {
      const int col = c0 + n * 16;
      const float bv = bias ? bias[col] : 0.0f;
#pragma unroll
      for (int m = 0; m < 8; ++m) {
#pragma unroll
        for (int i = 0; i < 4; ++i) {
          const int row = r0 + m * 16 + i;
          float g = sigmoidf_(acc[m][n][i] + bv);
          float sc = bf2f(scb[(size_t)row * 1536 + col]);
          float e = hp[(size_t)row * 512 + col] + g * sc;
          outf[(size_t)row * 512 + col] = e;
          outb[(size_t)row * 512 + col] = f2bf(e);
        }
      }
    }
  } else {
    // swizzled LDS C-stage (256x256 bf16 = 128 KiB, reuses whole lds), then
    // coalesced 16B-chunk stores.
    unsigned short* ob = outb;
    int ld = ldob, ncof = n0;
    const float* bp = bias;
    if constexpr (EPI == 2) {
      if (n0 >= 512) { ob = outb2; ld = ldob2; ncof = n0 - 512; bp = bias2; }
    }
    const int r0l = wm + ((lane >> 4) << 2);
    const int c0l = wn + lrow;
#pragma unroll
    for (int n = 0; n < 4; ++n) {
      const int col = c0l + n * 16;
      const float bv = bp ? bp[ncof + col] : 0.0f;
      const int g8 = col >> 3, c7 = col & 7;
#pragma unroll
      for (int m = 0; m < 8; ++m)
#pragma unroll
        for (int i = 0; i < 4; ++i) {
          const int row = r0l + m * 16 + i;
          lds[row * 256 + ((g8 ^ (row & 7)) << 3) + c7] = f2bf(acc[m][n][i] + bv);
        }
    }
    __syncthreads();
#pragma unroll
    for (int jj = 0; jj < 16; ++jj) {
      int c = jj * 512 + tid;   // 8192 chunks = 256 rows x 32 chunks(16B)
      int row = c >> 5;
      int slot = c & 31;
      u16x8 v = *(const u16x8*)&lds[row * 256 + ((slot ^ (row & 7)) << 3)];
      *(u16x8*)&ob[(size_t)(m0 + row) * ld + ncof + slot * 8] = v;
    }
  }
}

// ---------------- attention over the 2 neighbor states ----------------
__global__ void attn_fuse(const unsigned short* __restrict__ qkvl,
                          const unsigned short* __restrict__ qkvu,
                          unsigned short* __restrict__ ctx) {
  int t = blockIdx.x * blockDim.x + threadIdx.x;
  int g = t >> 4;  // (b,h)
  int l = t & 15;
  int b = g >> 2, h = g & 3;
  const size_t base = (size_t)b * 1536 + h * 128 + l * 8;
  u16x8 q0 = *(const u16x8*)(qkvl + base);
  u16x8 k0 = *(const u16x8*)(qkvl + base + 512);
  u16x8 v0 = *(const u16x8*)(qkvl + base + 1024);
  u16x8 q1 = *(const u16x8*)(qkvu + base);
  u16x8 k1 = *(const u16x8*)(qkvu + base + 512);
  u16x8 v1 = *(const u16x8*)(qkvu + base + 1024);
  float s00 = 0.f, s01 = 0.f, s10 = 0.f, s11 = 0.f;
  float v0f[8], v1f[8];
#pragma unroll
  for (int i = 0; i < 8; ++i) {
    float q0f = bf2f(q0[i]), q1f = bf2f(q1[i]);
    float k0f = bf2f(k0[i]), k1f = bf2f(k1[i]);
    v0f[i] = bf2f(v0[i]); v1f[i] = bf2f(v1[i]);
    s00 += q0f * k0f; s01 += q0f * k1f;
    s10 += q1f * k0f; s11 += q1f * k1f;
  }
#pragma unroll
  for (int off = 1; off < 16; off <<= 1) {
    s00 += __shfl_xor(s00, off);
    s01 += __shfl_xor(s01, off);
    s10 += __shfl_xor(s10, off);
    s11 += __shfl_xor(s11, off);
  }
  const float scale = 0.0883883476483184f;  // 1/sqrt(128)
  s00 *= scale; s01 *= scale; s10 *= scale; s11 *= scale;
  float m0 = fmaxf(s00, s01), m1 = fmaxf(s10, s11);
  float a00 = __expf(s00 - m0), a01 = __expf(s01 - m0);
  float a10 = __expf(s10 - m1), a11 = __expf(s11 - m1);
  float c0 = 0.5f * (a00 / (a00 + a01) + a10 / (a10 + a11));
  float c1 = 0.5f * (a01 / (a00 + a01) + a11 / (a10 + a11));
  u16x8 o;
#pragma unroll
  for (int i = 0; i < 8; ++i) o[i] = f2bf(c0 * v0f[i] + c1 * v1f[i]);
  *(u16x8*)(ctx + (size_t)b * 512 + h * 128 + l * 8) = o;
}

// ---------------- GRU elementwise finish ----------------
__global__ void gru_final(const unsigned short* __restrict__ gi,
                          const unsigned short* __restrict__ gh,
                          const float* __restrict__ enh,
                          float* __restrict__ out) {
  int t = blockIdx.x * blockDim.x + threadIdx.x;  // B*64 threads
  int b = t >> 6;
  int j = (t & 63) * 8;
  size_t gb = (size_t)b * 1536 + j;
  u16x8 ir = *(const u16x8*)(gi + gb);
  u16x8 iz = *(const u16x8*)(gi + gb + 512);
  u16x8 in_ = *(const u16x8*)(gi + gb + 1024);
  u16x8 hr = *(const u16x8*)(gh + gb);
  u16x8 hz = *(const u16x8*)(gh + gb + 512);
  u16x8 hn = *(const u16x8*)(gh + gb + 1024);
  size_t eb = (size_t)b * 512 + j;
  float4 e0 = *(const float4*)(enh + eb);
  float4 e1 = *(const float4*)(enh + eb + 4);
  float ef[8] = {e0.x, e0.y, e0.z, e0.w, e1.x, e1.y, e1.z, e1.w};
  float of[8];
#pragma unroll
  for (int i = 0; i < 8; ++i) {
    float r = sigmoidf_(bf2f(ir[i]) + bf2f(hr[i]));
    float z = sigmoidf_(bf2f(iz[i]) + bf2f(hz[i]));
    float n = tanhf(bf2f(in_[i]) + r * bf2f(hn[i]));
    of[i] = (1.0f - z) * n + z * ef[i];
  }
  *(float4*)(out + eb) = make_float4(of[0], of[1], of[2], of[3]);
  *(float4*)(out + eb + 4) = make_float4(of[4], of[5], of[6], of[7]);
}

extern "C" void kernel_launch(void* const* d_in, const int* in_sizes, int n_in,
                              void* d_out, int out_size, void* d_ws, size_t ws_size,
                              hipStream_t stream) {
  const float* x = (const float*)d_in[0];
  const float* hl = (const float*)d_in[1];
  const float* hu = (const float*)d_in[2];
  const float* hp = (const float*)d_in[3];
  const float* W_in = (const float*)d_in[4];
  const float* b_in = (const float*)d_in[5];
  const float* attn_in_w = (const float*)d_in[6];
  const float* attn_in_b = (const float*)d_in[7];
  const float* attn_out_w = (const float*)d_in[8];
  const float* attn_out_b = (const float*)d_in[9];
  const float* W_gate = (const float*)d_in[10];
  const float* b_gate = (const float*)d_in[11];
  const float* gru_w_ih = (const float*)d_in[12];
  const float* gru_w_hh = (const float*)d_in[13];
  const float* gru_b_ih = (const float*)d_in[14];
  const float* gru_b_hh = (const float*)d_in[15];

  char* ws = (char*)d_ws;
  size_t off = 0;
  auto alloc = [&](size_t bytes) {
    void* p = ws + off;
    off += (bytes + 255) & ~(size_t)255;
    return p;
  };
  // bf16 weights
  unsigned short* wComb = (unsigned short*)alloc((size_t)2048 * 128 * 2);  // [W_in; gru_w_ih]
  unsigned short* wAin  = (unsigned short*)alloc((size_t)1536 * 512 * 2);
  unsigned short* wAout = (unsigned short*)alloc((size_t)512 * 512 * 2);
  unsigned short* wGate = (unsigned short*)alloc((size_t)512 * 1536 * 2);
  unsigned short* wHh   = (unsigned short*)alloc((size_t)1536 * 512 * 2);
  // bf16 activations
  unsigned short* xb   = (unsigned short*)alloc((size_t)NB * 128 * 2);
  unsigned short* hlub = (unsigned short*)alloc((size_t)2 * NB * 512 * 2);   // [hl; hu]
  unsigned short* gate_in = (unsigned short*)alloc((size_t)NB * 1536 * 2);   // [hp|sc|xp]
  unsigned short* qkvb = (unsigned short*)alloc((size_t)2 * NB * 1536 * 2);  // [qkvl; qkvu]
  unsigned short* ctxb = (unsigned short*)alloc((size_t)NB * 512 * 2);
  float* enhf = (float*)alloc((size_t)NB * 512 * 4);
  unsigned short* enhb = (unsigned short*)alloc((size_t)NB * 512 * 2);
  unsigned short* qkvl = qkvb;
  unsigned short* qkvu = qkvb + (size_t)NB * 1536;
  unsigned short* gi = qkvl;  // reuse (qkv dead after attn_fuse)
  unsigned short* gh = qkvu;

  (void)ws_size; (void)in_sizes; (void)n_in; (void)out_size;

  const int T = 256;

  // single merged conversion launch (9 jobs)
  CvtJobs jobs;
  jobs.src[0] = W_in;       jobs.dst[0] = wComb;
  jobs.src[1] = gru_w_ih;   jobs.dst[1] = wComb + (size_t)512 * 128;
  jobs.src[2] = attn_in_w;  jobs.dst[2] = wAin;
  jobs.src[3] = attn_out_w; jobs.dst[3] = wAout;
  jobs.src[4] = W_gate;     jobs.dst[4] = wGate;
  jobs.src[5] = gru_w_hh;   jobs.dst[5] = wHh;
  jobs.src[6] = x;          jobs.dst[6] = xb;
  jobs.src[7] = hl;         jobs.dst[7] = hlub;
  jobs.src[8] = hu;         jobs.dst[8] = hlub + (size_t)NB * 512;
  cvt_multi<<<(CT + T - 1) / T, T, 0, stream>>>(jobs);
  pack_hp<<<NB * 64 / T, T, 0, stream>>>(hp, gate_in);

  const int MT = NB / 256;  // 64 M-tiles

  // G2 batched: qkv for [hl;hu], M=2*NB -> 128 M-tiles x 6 N-tiles = 768
  gemm_bt<0><<<6 * 2 * MT, dim3(512), 0, stream>>>(hlub, 512, wAin, 512, attn_in_b,
                                                   nullptr, 512, 6,
                                                   qkvb, 1536, nullptr, 0,
                                                   nullptr, nullptr, nullptr);
  // attention -> ctx_mean (bf16)
  attn_fuse<<<NB * NHEADS * 16 / T, T, 0, stream>>>(qkvl, qkvu, ctxb);
  // G4: spatial_combined -> gate_in cols 512..1023  (64x2 = 128 blocks)
  gemm_bt<0><<<2 * MT, dim3(512), 0, stream>>>(ctxb, 512, wAout, 512, attn_out_b,
                                               nullptr, 512, 2,
                                               gate_in + 512, 1536, nullptr, 0,
                                               nullptr, nullptr, nullptr);
  // G1+G6 fused: x @ [W_in; w_ih]^T, N=2048 (64x8 = 512 blocks)
  gemm_bt<2><<<8 * MT, dim3(512), 0, stream>>>(xb, 128, wComb, 128, b_in,
                                               gru_b_ih, 128, 8,
                                               gate_in + 1024, 1536, gi, 1536,
                                               nullptr, nullptr, nullptr);
  // G5: gate + enhanced (64x2 = 128 blocks)
  gemm_bt<1><<<2 * MT, dim3(512), 0, stream>>>(gate_in, 1536, wGate, 1536, b_gate,
                                               nullptr, 1536, 2,
                                               enhb, 512, nullptr, 0,
                                               enhf, hp, gate_in + 512);
  // G7: gh = enhanced @ w_hh^T + b_hh (64x6 = 384 blocks)
  gemm_bt<0><<<6 * MT, dim3(512), 0, stream>>>(enhb, 512, wHh, 512, gru_b_hh,
                                               nullptr, 512, 6,
                                               gh, 1536, nullptr, 0,
                                               nullptr, nullptr, nullptr);
  // final GRU blend
  gru_final<<<NB * 64 / T, T, 0, stream>>>(gi, gh, enhf, (float*)d_out);
}

// Round 8
// 300.311 us; speedup vs baseline: 1.3623x; 1.3623x over previous
//
#include <hip/hip_runtime.h>
#include <hip/hip_bf16.h>
#include <stdint.h>

// ImprovedLatticeRNNCell fused bf16-MFMA implementation, round 8.
// Two GEMM templates:
//  - gemm_big: 256x256/BK64, 8 waves, launch_bounds(512,1)  [VGPR cap 256]
//    for the large-grid GEMMs (qkv, G1G6, G7).
//  - gemm_bt:  128x128/BK64, 4 waves (R6-proven) for small-grid G4/G5.

#define NB 16384
#define NHEADS 4

typedef __attribute__((ext_vector_type(8))) __bf16 bf16x8;
typedef __attribute__((ext_vector_type(4))) float f32x4;
typedef __attribute__((ext_vector_type(8))) unsigned short u16x8;

__device__ __forceinline__ unsigned short f2bf(float f) {
  union { float f; unsigned int u; } v; v.f = f;
  unsigned int u = v.u;
  unsigned int r = (u + 0x7fffu + ((u >> 16) & 1u)) >> 16;
  return (unsigned short)r;
}
__device__ __forceinline__ float bf2f(unsigned short h) {
  union { unsigned int u; float f; } v; v.u = ((unsigned int)h) << 16;
  return v.f;
}
__device__ __forceinline__ float sigmoidf_(float x) {
  return 1.0f / (1.0f + __expf(-x));
}

// ---------------- merged f32 -> bf16 conversion (9 jobs, 1 launch) ----------
#define J0 (512 * 128 / 8)    // W_in -> wComb head
#define J1 (1536 * 128 / 8)   // gru_w_ih -> wComb tail
#define J2 (1536 * 512 / 8)   // attn_in_w
#define J3 (512 * 512 / 8)    // attn_out_w
#define J4 (512 * 1536 / 8)   // W_gate
#define J5 (1536 * 512 / 8)   // gru_w_hh
#define J6 (NB * 128 / 8)     // x
#define J7 (NB * 512 / 8)     // hl
#define J8 (NB * 512 / 8)     // hu
#define C1 (J0)
#define C2 (C1 + J1)
#define C3 (C2 + J2)
#define C4 (C3 + J3)
#define C5 (C4 + J4)
#define C6 (C5 + J5)
#define C7 (C6 + J6)
#define C8 (C7 + J7)
#define CT (C8 + J8)

struct CvtJobs {
  const float* src[9];
  unsigned short* dst[9];
};

__global__ void cvt_multi(CvtJobs j) {
  int g = blockIdx.x * blockDim.x + threadIdx.x;
  if (g >= CT) return;
  int k, base;
  if (g < C4) {
    if (g < C2) {
      if (g < C1) { k = 0; base = 0; } else { k = 1; base = C1; }
    } else {
      if (g < C3) { k = 2; base = C2; } else { k = 3; base = C3; }
    }
  } else {
    if (g < C6) {
      if (g < C5) { k = 4; base = C4; } else { k = 5; base = C5; }
    } else {
      if (g < C7) { k = 6; base = C6; }
      else if (g < C8) { k = 7; base = C7; }
      else { k = 8; base = C8; }
    }
  }
  int local = g - base;
  const float4* s = (const float4*)j.src[k] + (size_t)local * 2;
  float4 a = s[0], b = s[1];
  u16x8 o;
  o[0] = f2bf(a.x); o[1] = f2bf(a.y); o[2] = f2bf(a.z); o[3] = f2bf(a.w);
  o[4] = f2bf(b.x); o[5] = f2bf(b.y); o[6] = f2bf(b.z); o[7] = f2bf(b.w);
  *((u16x8*)j.dst[k] + local) = o;
}

// pack hidden_prev f32 [B,512] -> bf16 into gate_in [B,1536] cols 0..511
__global__ void pack_hp(const float* __restrict__ hp,
                        unsigned short* __restrict__ gate_in) {
  int t = blockIdx.x * blockDim.x + threadIdx.x;  // B*64 threads
  int b = t >> 6;
  int j = (t & 63) * 8;
  const float4* s = (const float4*)(hp + (size_t)b * 512 + j);
  float4 a = s[0], c = s[1];
  u16x8 o;
  o[0] = f2bf(a.x); o[1] = f2bf(a.y); o[2] = f2bf(a.z); o[3] = f2bf(a.w);
  o[4] = f2bf(c.x); o[5] = f2bf(c.y); o[6] = f2bf(c.z); o[7] = f2bf(c.w);
  *(u16x8*)(gate_in + (size_t)b * 1536 + j) = o;
}

__device__ __forceinline__ void gl_lds16(const unsigned short* g, unsigned short* l) {
  __builtin_amdgcn_global_load_lds(
      (const __attribute__((address_space(1))) void*)g,
      (__attribute__((address_space(3))) void*)l, 16, 0, 0);
}

// ============== 256x256 GEMM (large grids) ==============
// EPI 0: outb = bf16(acc+bias)   (swizzled LDS-staged coalesced store)
// EPI 2: router: global col<512 -> outb (ldob, bias), else outb2 (ldob2, bias2)
template <int EPI>
__global__ __launch_bounds__(512, 1) void gemm_big(
    const unsigned short* __restrict__ A, int lda,
    const unsigned short* __restrict__ W, int ldw,
    const float* __restrict__ bias, const float* __restrict__ bias2,
    int K, int ntx,
    unsigned short* __restrict__ outb, int ldob,
    unsigned short* __restrict__ outb2, int ldob2) {
  __shared__ unsigned short lds[65536];  // 128 KiB: A dbuf | W dbuf; C-stage reuse
  unsigned short* Asb = lds;             // [2][16384]
  unsigned short* Wsb = lds + 32768;     // [2][16384]
  const int tid = threadIdx.x;
  const int lane = tid & 63;
  const int wave = tid >> 6;  // 0..7

  // XCD-aware bijective swizzle (gridDim.x always a multiple of 8 here)
  const int nwg = gridDim.x;
  const int cpx = nwg >> 3;
  const int bid = blockIdx.x;
  const int id = (bid & 7) * cpx + (bid >> 3);
  const int bx = id % ntx;
  const int by = id / ntx;

  const int m0 = by * 256;
  const int n0 = bx * 256;
  const int wm = (wave >> 2) * 128;  // 0 or 128
  const int wn = (wave & 3) * 64;    // 0,64,128,192

  f32x4 acc[8][4] = {};

  // staging: thread covers rows srow+64i, 16B slot sslot (inverse-swizzled).
  const int srow = tid >> 3;                 // 0..63
  const int sslot = (tid & 7) ^ (srow & 7);  // source slot
  const unsigned short* Ag = A + (size_t)(m0 + srow) * lda + sslot * 8;
  const unsigned short* Wg = W + (size_t)(n0 + srow) * ldw + sslot * 8;
  unsigned short* Asd = Asb + tid * 8;
  unsigned short* Wsd = Wsb + tid * 8;

  auto stage = [&](int buf, int k0) {
#pragma unroll
    for (int i = 0; i < 4; ++i)
      gl_lds16(Ag + (size_t)(i * 64) * lda + k0, Asd + buf * 16384 + i * 4096);
#pragma unroll
    for (int i = 0; i < 4; ++i)
      gl_lds16(Wg + (size_t)(i * 64) * ldw + k0, Wsd + buf * 16384 + i * 4096);
  };

  stage(0, 0);
  int cur = 0;
  const int lrow = lane & 15;
  const int kq = (lane >> 4) * 8;  // shorts
  const int sw = (lrow & 7) << 3;  // read-side swizzle (shorts)

  for (int k0 = 0; k0 < K; k0 += 64) {
    if (k0 + 64 < K) {
      stage(cur ^ 1, k0 + 64);
      // 8 loads/stage: wait for the 8 oldest (current buffer), keep 8 in flight
      asm volatile("s_waitcnt vmcnt(8)" ::: "memory");
    } else {
      asm volatile("s_waitcnt vmcnt(0)" ::: "memory");
    }
    __builtin_amdgcn_s_barrier();
    const unsigned short* Ab = Asb + cur * 16384;
    const unsigned short* Wb = Wsb + cur * 16384;

    bf16x8 wfr[4][2], afr[4][2];
#pragma unroll
    for (int n = 0; n < 4; ++n)
#pragma unroll
      for (int kk = 0; kk < 2; ++kk)
        wfr[n][kk] = *(const bf16x8*)&Wb[(wn + n * 16 + lrow) * 64 + ((kk * 32 + kq) ^ sw)];
#pragma unroll
    for (int m = 0; m < 4; ++m)
#pragma unroll
      for (int kk = 0; kk < 2; ++kk)
        afr[m][kk] = *(const bf16x8*)&Ab[(wm + m * 16 + lrow) * 64 + ((kk * 32 + kq) ^ sw)];
    __builtin_amdgcn_s_setprio(1);
#pragma unroll
    for (int m = 0; m < 4; ++m)
#pragma unroll
      for (int n = 0; n < 4; ++n)
#pragma unroll
        for (int kk = 0; kk < 2; ++kk)
          acc[m][n] = __builtin_amdgcn_mfma_f32_16x16x32_bf16(afr[m][kk], wfr[n][kk],
                                                              acc[m][n], 0, 0, 0);
    __builtin_amdgcn_s_setprio(0);
    __builtin_amdgcn_sched_barrier(0);
    // sub-phase 1: reload A frags for rows wm+64..wm+127
#pragma unroll
    for (int m = 0; m < 4; ++m)
#pragma unroll
      for (int kk = 0; kk < 2; ++kk)
        afr[m][kk] = *(const bf16x8*)&Ab[(wm + 64 + m * 16 + lrow) * 64 + ((kk * 32 + kq) ^ sw)];
    __builtin_amdgcn_s_setprio(1);
#pragma unroll
    for (int m = 0; m < 4; ++m)
#pragma unroll
      for (int n = 0; n < 4; ++n)
#pragma unroll
        for (int kk = 0; kk < 2; ++kk)
          acc[m + 4][n] = __builtin_amdgcn_mfma_f32_16x16x32_bf16(afr[m][kk], wfr[n][kk],
                                                                  acc[m + 4][n], 0, 0, 0);
    __builtin_amdgcn_s_setprio(0);
    __builtin_amdgcn_s_barrier();
    cur ^= 1;
  }

  // swizzled LDS C-stage (256x256 bf16 = 128 KiB), then coalesced stores.
  unsigned short* ob = outb;
  int ld = ldob, ncof = n0;
  const float* bp = bias;
  if constexpr (EPI == 2) {
    if (n0 >= 512) { ob = outb2; ld = ldob2; ncof = n0 - 512; bp = bias2; }
  }
  const int r0l = wm + ((lane >> 4) << 2);
  const int c0l = wn + lrow;
#pragma unroll
  for (int n = 0; n < 4; ++n) {
    const int col = c0l + n * 16;
    const float bv = bp ? bp[ncof + col] : 0.0f;
    const int g8 = col >> 3, c7 = col & 7;
#pragma unroll
    for (int m = 0; m < 8; ++m)
#pragma unroll
      for (int i = 0; i < 4; ++i) {
        const int row = r0l + m * 16 + i;
        lds[row * 256 + ((g8 ^ (row & 7)) << 3) + c7] = f2bf(acc[m][n][i] + bv);
      }
  }
  __syncthreads();
#pragma unroll
  for (int jj = 0; jj < 16; ++jj) {
    int c = jj * 512 + tid;   // 8192 chunks = 256 rows x 32 chunks(16B)
    int row = c >> 5;
    int slot = c & 31;
    u16x8 v = *(const u16x8*)&lds[row * 256 + ((slot ^ (row & 7)) << 3)];
    *(u16x8*)&ob[(size_t)(m0 + row) * ld + ncof + slot * 8] = v;
  }
}

// ============== 128x128 GEMM (small grids: G4, G5) — R6-proven ==============
// EPI 0: outb[row*ldob+col] = bf16(v)  (coalesced LDS epilogue)
// EPI 1: gate epilogue (sigmoid, enhanced blend) -> outf(f32) + outb(bf16)
template <int EPI>
__global__ __launch_bounds__(256, 2) void gemm_bt(
    const unsigned short* __restrict__ A, int lda,
    const unsigned short* __restrict__ W, int ldw,
    const float* __restrict__ bias, int K, int ntx,
    unsigned short* __restrict__ outb, int ldob,
    float* __restrict__ outf,
    const float* __restrict__ hp,
    const unsigned short* __restrict__ scb) {
  __shared__ unsigned short As[2][128 * 64];
  __shared__ unsigned short Ws[2][128 * 64];
  const int tid = threadIdx.x;
  const int lane = tid & 63;
  const int wave = tid >> 6;

  const int nwg = gridDim.x;
  const int cpx = nwg >> 3;
  const int bid = blockIdx.x;
  const int id = (bid & 7) * cpx + (bid >> 3);
  const int bx = id % ntx;
  const int by = id / ntx;

  const int m0 = by * 128;
  const int n0 = bx * 128;
  const int wm = (wave >> 1) * 64;
  const int wn = (wave & 1) * 64;

  f32x4 acc[4][4] = {};

  const int srow = tid >> 3;                 // 0..31
  const int sslot = (tid & 7) ^ (srow & 7);  // inverse-swizzled source slot
  const unsigned short* Ag = A + (size_t)(m0 + srow) * lda + sslot * 8;
  const unsigned short* Wg = W + (size_t)(n0 + srow) * ldw + sslot * 8;
  unsigned short* Asd = &As[0][tid * 8];
  unsigned short* Wsd = &Ws[0][tid * 8];

  auto stage = [&](int buf, int k0) {
#pragma unroll
    for (int i = 0; i < 4; ++i) {
      gl_lds16(Ag + (size_t)(i * 32) * lda + k0, Asd + buf * 8192 + i * 2048);
      gl_lds16(Wg + (size_t)(i * 32) * ldw + k0, Wsd + buf * 8192 + i * 2048);
    }
  };

  stage(0, 0);
  int cur = 0;
  const int lrow = lane & 15;
  const int kq = (lane >> 4) * 8;  // shorts
  const int sw = (lrow & 7) << 3;  // read-side swizzle (shorts)

  for (int k0 = 0; k0 < K; k0 += 64) {
    if (k0 + 64 < K) {
      stage(cur ^ 1, k0 + 64);
      asm volatile("s_waitcnt vmcnt(8)" ::: "memory");
    } else {
      asm volatile("s_waitcnt vmcnt(0)" ::: "memory");
    }
    __builtin_amdgcn_s_barrier();
#pragma unroll
    for (int kk = 0; kk < 2; ++kk) {
      const int kr = kk * 32 + kq;
      const int ki = kr ^ sw;
      bf16x8 af[4], wf[4];
#pragma unroll
      for (int m = 0; m < 4; ++m)
        af[m] = *(const bf16x8*)&As[cur][(wm + m * 16 + lrow) * 64 + ki];
#pragma unroll
      for (int n = 0; n < 4; ++n)
        wf[n] = *(const bf16x8*)&Ws[cur][(wn + n * 16 + lrow) * 64 + ki];
#pragma unroll
      for (int m = 0; m < 4; ++m)
#pragma unroll
        for (int n = 0; n < 4; ++n)
          acc[m][n] = __builtin_amdgcn_mfma_f32_16x16x32_bf16(af[m], wf[n],
                                                              acc[m][n], 0, 0, 0);
    }
    __builtin_amdgcn_s_barrier();
    cur ^= 1;
  }

  if constexpr (EPI == 1) {
    const int r0 = m0 + wm + ((lane >> 4) << 2);
    const int c0 = n0 + wn + lrow;
#pragma unroll
    for (int n = 0; n < 4; ++n) {
      const int col = c0 + n * 16;
      const float bv = bias ? bias[col] : 0.0f;
#pragma unroll
      for (int m = 0; m < 4; ++m) {
#pragma unroll
        for (int i = 0; i < 4; ++i) {
          const int row = r0 + m * 16 + i;
          float g = sigmoidf_(acc[m][n][i] + bv);
          float sc = bf2f(scb[(size_t)row * 1536 + col]);
          float e = hp[(size_t)row * 512 + col] + g * sc;
          outf[(size_t)row * 512 + col] = e;
          outb[(size_t)row * 512 + col] = f2bf(e);
        }
      }
    }
  } else {
    unsigned short* Cs = &As[0][0];  // 128*128 shorts = 32 KB
    const int r0l = wm + ((lane >> 4) << 2);
    const int c0l = wn + lrow;
#pragma unroll
    for (int n = 0; n < 4; ++n) {
      const int col = c0l + n * 16;
      const float bv = bias ? bias[n0 + col] : 0.0f;
#pragma unroll
      for (int m = 0; m < 4; ++m)
#pragma unroll
        for (int i = 0; i < 4; ++i)
          Cs[(r0l + m * 16 + i) * 128 + col] = f2bf(acc[m][n][i] + bv);
    }
    __syncthreads();
#pragma unroll
    for (int jj = 0; jj < 8; ++jj) {
      int c = jj * 256 + tid;   // 2048 chunks = 128 rows x 16 chunks(16B)
      int row = c >> 4;
      int slot = c & 15;
      u16x8 v = *(const u16x8*)&Cs[row * 128 + slot * 8];
      *(u16x8*)&outb[(size_t)(m0 + row) * ldob + n0 + slot * 8] = v;
    }
  }
}

// ---------------- attention over the 2 neighbor states ----------------
__global__ void attn_fuse(const unsigned short* __restrict__ qkvl,
                          const unsigned short* __restrict__ qkvu,
                          unsigned short* __restrict__ ctx) {
  int t = blockIdx.x * blockDim.x + threadIdx.x;
  int g = t >> 4;  // (b,h)
  int l = t & 15;
  int b = g >> 2, h = g & 3;
  const size_t base = (size_t)b * 1536 + h * 128 + l * 8;
  u16x8 q0 = *(const u16x8*)(qkvl + base);
  u16x8 k0 = *(const u16x8*)(qkvl + base + 512);
  u16x8 v0 = *(const u16x8*)(qkvl + base + 1024);
  u16x8 q1 = *(const u16x8*)(qkvu + base);
  u16x8 k1 = *(const u16x8*)(qkvu + base + 512);
  u16x8 v1 = *(const u16x8*)(qkvu + base + 1024);
  float s00 = 0.f, s01 = 0.f, s10 = 0.f, s11 = 0.f;
  float v0f[8], v1f[8];
#pragma unroll
  for (int i = 0; i < 8; ++i) {
    float q0f = bf2f(q0[i]), q1f = bf2f(q1[i]);
    float k0f = bf2f(k0[i]), k1f = bf2f(k1[i]);
    v0f[i] = bf2f(v0[i]); v1f[i] = bf2f(v1[i]);
    s00 += q0f * k0f; s01 += q0f * k1f;
    s10 += q1f * k0f; s11 += q1f * k1f;
  }
#pragma unroll
  for (int off = 1; off < 16; off <<= 1) {
    s00 += __shfl_xor(s00, off);
    s01 += __shfl_xor(s01, off);
    s10 += __shfl_xor(s10, off);
    s11 += __shfl_xor(s11, off);
  }
  const float scale = 0.0883883476483184f;  // 1/sqrt(128)
  s00 *= scale; s01 *= scale; s10 *= scale; s11 *= scale;
  float m0 = fmaxf(s00, s01), m1 = fmaxf(s10, s11);
  float a00 = __expf(s00 - m0), a01 = __expf(s01 - m0);
  float a10 = __expf(s10 - m1), a11 = __expf(s11 - m1);
  float c0 = 0.5f * (a00 / (a00 + a01) + a10 / (a10 + a11));
  float c1 = 0.5f * (a01 / (a00 + a01) + a11 / (a10 + a11));
  u16x8 o;
#pragma unroll
  for (int i = 0; i < 8; ++i) o[i] = f2bf(c0 * v0f[i] + c1 * v1f[i]);
  *(u16x8*)(ctx + (size_t)b * 512 + h * 128 + l * 8) = o;
}

// ---------------- GRU elementwise finish ----------------
__global__ void gru_final(const unsigned short* __restrict__ gi,
                          const unsigned short* __restrict__ gh,
                          const float* __restrict__ enh,
                          float* __restrict__ out) {
  int t = blockIdx.x * blockDim.x + threadIdx.x;  // B*64 threads
  int b = t >> 6;
  int j = (t & 63) * 8;
  size_t gb = (size_t)b * 1536 + j;
  u16x8 ir = *(const u16x8*)(gi + gb);
  u16x8 iz = *(const u16x8*)(gi + gb + 512);
  u16x8 in_ = *(const u16x8*)(gi + gb + 1024);
  u16x8 hr = *(const u16x8*)(gh + gb);
  u16x8 hz = *(const u16x8*)(gh + gb + 512);
  u16x8 hn = *(const u16x8*)(gh + gb + 1024);
  size_t eb = (size_t)b * 512 + j;
  float4 e0 = *(const float4*)(enh + eb);
  float4 e1 = *(const float4*)(enh + eb + 4);
  float ef[8] = {e0.x, e0.y, e0.z, e0.w, e1.x, e1.y, e1.z, e1.w};
  float of[8];
#pragma unroll
  for (int i = 0; i < 8; ++i) {
    float r = sigmoidf_(bf2f(ir[i]) + bf2f(hr[i]));
    float z = sigmoidf_(bf2f(iz[i]) + bf2f(hz[i]));
    float n = tanhf(bf2f(in_[i]) + r * bf2f(hn[i]));
    of[i] = (1.0f - z) * n + z * ef[i];
  }
  *(float4*)(out + eb) = make_float4(of[0], of[1], of[2], of[3]);
  *(float4*)(out + eb + 4) = make_float4(of[4], of[5], of[6], of[7]);
}

extern "C" void kernel_launch(void* const* d_in, const int* in_sizes, int n_in,
                              void* d_out, int out_size, void* d_ws, size_t ws_size,
                              hipStream_t stream) {
  const float* x = (const float*)d_in[0];
  const float* hl = (const float*)d_in[1];
  const float* hu = (const float*)d_in[2];
  const float* hp = (const float*)d_in[3];
  const float* W_in = (const float*)d_in[4];
  const float* b_in = (const float*)d_in[5];
  const float* attn_in_w = (const float*)d_in[6];
  const float* attn_in_b = (const float*)d_in[7];
  const float* attn_out_w = (const float*)d_in[8];
  const float* attn_out_b = (const float*)d_in[9];
  const float* W_gate = (const float*)d_in[10];
  const float* b_gate = (const float*)d_in[11];
  const float* gru_w_ih = (const float*)d_in[12];
  const float* gru_w_hh = (const float*)d_in[13];
  const float* gru_b_ih = (const float*)d_in[14];
  const float* gru_b_hh = (const float*)d_in[15];

  char* ws = (char*)d_ws;
  size_t off = 0;
  auto alloc = [&](size_t bytes) {
    void* p = ws + off;
    off += (bytes + 255) & ~(size_t)255;
    return p;
  };
  // bf16 weights
  unsigned short* wComb = (unsigned short*)alloc((size_t)2048 * 128 * 2);  // [W_in; gru_w_ih]
  unsigned short* wAin  = (unsigned short*)alloc((size_t)1536 * 512 * 2);
  unsigned short* wAout = (unsigned short*)alloc((size_t)512 * 512 * 2);
  unsigned short* wGate = (unsigned short*)alloc((size_t)512 * 1536 * 2);
  unsigned short* wHh   = (unsigned short*)alloc((size_t)1536 * 512 * 2);
  // bf16 activations
  unsigned short* xb   = (unsigned short*)alloc((size_t)NB * 128 * 2);
  unsigned short* hlub = (unsigned short*)alloc((size_t)2 * NB * 512 * 2);   // [hl; hu]
  unsigned short* gate_in = (unsigned short*)alloc((size_t)NB * 1536 * 2);   // [hp|sc|xp]
  unsigned short* qkvb = (unsigned short*)alloc((size_t)2 * NB * 1536 * 2);  // [qkvl; qkvu]
  unsigned short* ctxb = (unsigned short*)alloc((size_t)NB * 512 * 2);
  float* enhf = (float*)alloc((size_t)NB * 512 * 4);
  unsigned short* enhb = (unsigned short*)alloc((size_t)NB * 512 * 2);
  unsigned short* qkvl = qkvb;
  unsigned short* qkvu = qkvb + (size_t)NB * 1536;
  unsigned short* gi = qkvl;  // reuse (qkv dead after attn_fuse)
  unsigned short* gh = qkvu;

  (void)ws_size; (void)in_sizes; (void)n_in; (void)out_size;

  const int T = 256;

  // single merged conversion launch (9 jobs)
  CvtJobs jobs;
  jobs.src[0] = W_in;       jobs.dst[0] = wComb;
  jobs.src[1] = gru_w_ih;   jobs.dst[1] = wComb + (size_t)512 * 128;
  jobs.src[2] = attn_in_w;  jobs.dst[2] = wAin;
  jobs.src[3] = attn_out_w; jobs.dst[3] = wAout;
  jobs.src[4] = W_gate;     jobs.dst[4] = wGate;
  jobs.src[5] = gru_w_hh;   jobs.dst[5] = wHh;
  jobs.src[6] = x;          jobs.dst[6] = xb;
  jobs.src[7] = hl;         jobs.dst[7] = hlub;
  jobs.src[8] = hu;         jobs.dst[8] = hlub + (size_t)NB * 512;
  cvt_multi<<<(CT + T - 1) / T, T, 0, stream>>>(jobs);
  pack_hp<<<NB * 64 / T, T, 0, stream>>>(hp, gate_in);

  const int MTB = NB / 256;   // 64 256-tiles
  const int MTS = NB / 128;   // 128 128-tiles

  // G2 batched: qkv for [hl;hu], M=2*NB -> 128x6 = 768 blocks (256^2)
  gemm_big<0><<<6 * 2 * MTB, dim3(512), 0, stream>>>(hlub, 512, wAin, 512,
                                                     attn_in_b, nullptr, 512, 6,
                                                     qkvb, 1536, nullptr, 0);
  // attention -> ctx_mean (bf16)
  attn_fuse<<<NB * NHEADS * 16 / T, T, 0, stream>>>(qkvl, qkvu, ctxb);
  // G4: spatial_combined -> gate_in cols 512..1023  (128^2, 512 blocks)
  gemm_bt<0><<<4 * MTS, T, 0, stream>>>(ctxb, 512, wAout, 512, attn_out_b,
                                        512, 4,
                                        gate_in + 512, 1536,
                                        nullptr, nullptr, nullptr);
  // G1+G6 fused: x @ [W_in; w_ih]^T, N=2048 (256^2, 8x64 = 512 blocks)
  gemm_big<2><<<8 * MTB, dim3(512), 0, stream>>>(xb, 128, wComb, 128,
                                                 b_in, gru_b_ih, 128, 8,
                                                 gate_in + 1024, 1536, gi, 1536);
  // G5: gate + enhanced (128^2, 512 blocks)
  gemm_bt<1><<<4 * MTS, T, 0, stream>>>(gate_in, 1536, wGate, 1536, b_gate,
                                        1536, 4,
                                        enhb, 512,
                                        enhf, hp, gate_in + 512);
  // G7: gh = enhanced @ w_hh^T + b_hh (256^2, 6x64 = 384 blocks)
  gemm_big<0><<<6 * MTB, dim3(512), 0, stream>>>(enhb, 512, wHh, 512,
                                                 gru_b_hh, nullptr, 512, 6,
                                                 gh, 1536, nullptr, 0);
  // final GRU blend
  gru_final<<<NB * 64 / T, T, 0, stream>>>(gi, gh, enhf, (float*)d_out);
}

// Round 10
// 299.662 us; speedup vs baseline: 1.3653x; 1.0022x over previous
//
#include <hip/hip_runtime.h>
#include <hip/hip_bf16.h>
#include <stdint.h>

// ImprovedLatticeRNNCell, round 10.
// gemm_big: 256x256/BK64, 8 waves, 4-phase quadrant schedule:
//   phase q computes C-quadrant q (p0=AlxBl, p1=AlxBh, p2=AhxBh, p3=AhxBl);
//   every wave reads the SAME half at each phase (wave-uniform), so counted
//   vmcnt(4) waits at p0/p3 are race-free. Stages: Al',Bl' @p0, Bh' @p1,
//   Ah' @p2. Double-buffered LDS, XOR swizzle, XCD swizzle, setprio MFMA.
// gemm_bt: 128x128 R6-proven for small-grid G4/G5.

#define NB 16384
#define NHEADS 4

typedef __attribute__((ext_vector_type(8))) __bf16 bf16x8;
typedef __attribute__((ext_vector_type(4))) float f32x4;
typedef __attribute__((ext_vector_type(8))) unsigned short u16x8;

__device__ __forceinline__ unsigned short f2bf(float f) {
  union { float f; unsigned int u; } v; v.f = f;
  unsigned int u = v.u;
  unsigned int r = (u + 0x7fffu + ((u >> 16) & 1u)) >> 16;
  return (unsigned short)r;
}
__device__ __forceinline__ float bf2f(unsigned short h) {
  union { unsigned int u; float f; } v; v.u = ((unsigned int)h) << 16;
  return v.f;
}
__device__ __forceinline__ float sigmoidf_(float x) {
  return 1.0f / (1.0f + __expf(-x));
}

// ---------------- merged f32 -> bf16 conversion (9 jobs, 1 launch) ----------
#define J0 (512 * 128 / 8)
#define J1 (1536 * 128 / 8)
#define J2 (1536 * 512 / 8)
#define J3 (512 * 512 / 8)
#define J4 (512 * 1536 / 8)
#define J5 (1536 * 512 / 8)
#define J6 (NB * 128 / 8)
#define J7 (NB * 512 / 8)
#define J8 (NB * 512 / 8)
#define C1 (J0)
#define C2 (C1 + J1)
#define C3 (C2 + J2)
#define C4 (C3 + J3)
#define C5 (C4 + J4)
#define C6 (C5 + J5)
#define C7 (C6 + J6)
#define C8 (C7 + J7)
#define CT (C8 + J8)

struct CvtJobs {
  const float* src[9];
  unsigned short* dst[9];
};

__global__ void cvt_multi(CvtJobs j) {
  int g = blockIdx.x * blockDim.x + threadIdx.x;
  if (g >= CT) return;
  int k, base;
  if (g < C4) {
    if (g < C2) {
      if (g < C1) { k = 0; base = 0; } else { k = 1; base = C1; }
    } else {
      if (g < C3) { k = 2; base = C2; } else { k = 3; base = C3; }
    }
  } else {
    if (g < C6) {
      if (g < C5) { k = 4; base = C4; } else { k = 5; base = C5; }
    } else {
      if (g < C7) { k = 6; base = C6; }
      else if (g < C8) { k = 7; base = C7; }
      else { k = 8; base = C8; }
    }
  }
  int local = g - base;
  const float4* s = (const float4*)j.src[k] + (size_t)local * 2;
  float4 a = s[0], b = s[1];
  u16x8 o;
  o[0] = f2bf(a.x); o[1] = f2bf(a.y); o[2] = f2bf(a.z); o[3] = f2bf(a.w);
  o[4] = f2bf(b.x); o[5] = f2bf(b.y); o[6] = f2bf(b.z); o[7] = f2bf(b.w);
  *((u16x8*)j.dst[k] + local) = o;
}

__global__ void pack_hp(const float* __restrict__ hp,
                        unsigned short* __restrict__ gate_in) {
  int t = blockIdx.x * blockDim.x + threadIdx.x;
  int b = t >> 6;
  int j = (t & 63) * 8;
  const float4* s = (const float4*)(hp + (size_t)b * 512 + j);
  float4 a = s[0], c = s[1];
  u16x8 o;
  o[0] = f2bf(a.x); o[1] = f2bf(a.y); o[2] = f2bf(a.z); o[3] = f2bf(a.w);
  o[4] = f2bf(c.x); o[5] = f2bf(c.y); o[6] = f2bf(c.z); o[7] = f2bf(c.w);
  *(u16x8*)(gate_in + (size_t)b * 1536 + j) = o;
}

__device__ __forceinline__ void gl_lds16(const unsigned short* g, unsigned short* l) {
  __builtin_amdgcn_global_load_lds(
      (const __attribute__((address_space(1))) void*)g,
      (__attribute__((address_space(3))) void*)l, 16, 0, 0);
}

// ============== 256x256 GEMM, 4-phase quadrant schedule ==============
template <int EPI>
__global__ __launch_bounds__(512, 1) void gemm_big(
    const unsigned short* __restrict__ A, int lda,
    const unsigned short* __restrict__ W, int ldw,
    const float* __restrict__ bias, const float* __restrict__ bias2,
    int K, int ntx,
    unsigned short* __restrict__ outb, int ldob,
    unsigned short* __restrict__ outb2, int ldob2) {
  __shared__ unsigned short lds[65536];  // A dbuf [2][16384] | B dbuf [2][16384]
  unsigned short* Asb = lds;
  unsigned short* Bsb = lds + 32768;
  const int tid = threadIdx.x;
  const int lane = tid & 63;
  const int wave = tid >> 6;

  const int nwg = gridDim.x;
  const int cpx = nwg >> 3;
  const int bid = blockIdx.x;
  const int id = (bid & 7) * cpx + (bid >> 3);
  const int bx = id % ntx;
  const int by = id / ntx;

  const int m0 = by * 256;
  const int n0 = bx * 256;
  const int ar0 = (wave >> 2) * 64;  // A row offset within each half
  const int br0 = (wave & 3) * 32;   // B col offset within each half

  f32x4 acc[4][4][2] = {};  // [quadrant][m][n]

  // staging: linear LDS dest (row*64 + slot*8), inverse-swizzled source slot.
  const int srow = tid >> 3;                 // 0..63
  const int presw = (tid & 7) ^ (srow & 7);
  const unsigned short* Ag = A + (size_t)(m0 + srow) * lda + presw * 8;
  const unsigned short* Wg = W + (size_t)(n0 + srow) * ldw + presw * 8;
  unsigned short* Asd = Asb + tid * 8;
  unsigned short* Wsd = Bsb + tid * 8;

  auto stageA = [&](int buf, int h, int k0) {
    const unsigned short* s = Ag + (size_t)(h * 128) * lda + k0;
    unsigned short* d = Asd + buf * 16384 + h * 8192;
    gl_lds16(s, d);
    gl_lds16(s + (size_t)64 * lda, d + 4096);
  };
  auto stageB = [&](int buf, int h, int k0) {
    const unsigned short* s = Wg + (size_t)(h * 128) * ldw + k0;
    unsigned short* d = Wsd + buf * 16384 + h * 8192;
    gl_lds16(s, d);
    gl_lds16(s + (size_t)64 * ldw, d + 4096);
  };

  const int lrow = lane & 15;
  const int kq = (lane >> 4) * 8;
  const int sw = (lrow & 7) << 3;
  const int NT = K >> 6;

  // prologue: oldest {Alow,Blow}, newest {Bhigh,Ahigh}; drain oldest 4.
  stageA(0, 0, 0);
  stageB(0, 0, 0);
  stageB(0, 1, 0);
  stageA(0, 1, 0);
  asm volatile("s_waitcnt vmcnt(4)" ::: "memory");
  __builtin_amdgcn_s_barrier();

  bf16x8 a[4][2], b0[2][2], b1[2][2];

#define RD_A(X, H)                                                            \
  _Pragma("unroll") for (int m = 0; m < 4; ++m)                               \
  _Pragma("unroll") for (int kk = 0; kk < 2; ++kk)                            \
      a[m][kk] = *(const bf16x8*)&Asb[(X) * 16384 +                           \
                                      ((H) * 128 + ar0 + m * 16 + lrow) * 64 +\
                                      ((kk * 32 + kq) ^ sw)];
#define RD_B(X, H, DST)                                                       \
  _Pragma("unroll") for (int n = 0; n < 2; ++n)                               \
  _Pragma("unroll") for (int kk = 0; kk < 2; ++kk)                            \
      DST[n][kk] = *(const bf16x8*)&Bsb[(X) * 16384 +                         \
                                        ((H) * 128 + br0 + n * 16 + lrow) * 64 + \
                                        ((kk * 32 + kq) ^ sw)];
#define MFMA_Q(Q, BF)                                                         \
  __builtin_amdgcn_s_setprio(1);                                              \
  _Pragma("unroll") for (int m = 0; m < 4; ++m)                               \
  _Pragma("unroll") for (int n = 0; n < 2; ++n)                               \
  _Pragma("unroll") for (int kk = 0; kk < 2; ++kk)                            \
      acc[Q][m][n] = __builtin_amdgcn_mfma_f32_16x16x32_bf16(                 \
          a[m][kk], BF[n][kk], acc[Q][m][n], 0, 0, 0);                        \
  __builtin_amdgcn_s_setprio(0);
#define LGKM0                                                                 \
  asm volatile("s_waitcnt lgkmcnt(0)" ::: "memory");                          \
  __builtin_amdgcn_sched_barrier(0);
#define BAR __builtin_amdgcn_s_barrier();

  for (int t = 0; t < NT - 1; ++t) {
    const int X = t & 1, Y = X ^ 1;
    const int kn = (t + 1) << 6;
    // p0: quadrant (Alow x Blow). stage Alow',Blow'. vmcnt(4) drains
    //     Bhigh(t),Ahigh(t) -> covers p1 and p2 reads.
    RD_A(X, 0)
    RD_B(X, 0, b0)
    stageA(Y, 0, kn);
    stageB(Y, 0, kn);
    asm volatile("s_waitcnt vmcnt(4)" ::: "memory");
    BAR LGKM0
    MFMA_Q(0, b0)
    BAR
    // p1: quadrant (Alow x Bhigh). stage Bhigh'.
    RD_B(X, 1, b1)
    stageB(Y, 1, kn);
    BAR LGKM0
    MFMA_Q(1, b1)
    BAR
    // p2: quadrant (Ahigh x Bhigh). stage Ahigh'.
    RD_A(X, 1)
    stageA(Y, 1, kn);
    BAR LGKM0
    MFMA_Q(2, b1)
    BAR
    // p3: quadrant (Ahigh x Blow), regs only. vmcnt(4) drains Alow',Blow'.
    asm volatile("s_waitcnt vmcnt(4)" ::: "memory");
    BAR
    __builtin_amdgcn_sched_barrier(0);
    MFMA_Q(3, b0)
    BAR
  }
  // tail: no staging. vmcnt(0) after p0 drains Bhigh,Ahigh of last tile.
  {
    const int X = (NT - 1) & 1;
    RD_A(X, 0)
    RD_B(X, 0, b0)
    asm volatile("s_waitcnt vmcnt(0)" ::: "memory");
    BAR LGKM0
    MFMA_Q(0, b0)
    RD_B(X, 1, b1)
    LGKM0
    MFMA_Q(1, b1)
    RD_A(X, 1)
    LGKM0
    MFMA_Q(2, b1)
    MFMA_Q(3, b0)
  }
#undef RD_A
#undef RD_B
#undef MFMA_Q
#undef LGKM0
#undef BAR

  // swizzled LDS C-stage (256x256 bf16 = 128 KiB), then coalesced stores.
  __syncthreads();
  unsigned short* ob = outb;
  int ld = ldob, ncof = n0;
  const float* bp = bias;
  if constexpr (EPI == 2) {
    if (n0 >= 512) { ob = outb2; ld = ldob2; ncof = n0 - 512; bp = bias2; }
  }
  const int qr[4] = {0, 0, 128, 128};
  const int qc[4] = {0, 128, 128, 0};
  const int ri = (lane >> 4) << 2;
#pragma unroll
  for (int q = 0; q < 4; ++q) {
#pragma unroll
    for (int n = 0; n < 2; ++n) {
      const int col = qc[q] + br0 + n * 16 + lrow;
      const float bv = bp ? bp[ncof + col] : 0.0f;
      const int g8 = col >> 3, c7 = col & 7;
#pragma unroll
      for (int m = 0; m < 4; ++m)
#pragma unroll
        for (int i = 0; i < 4; ++i) {
          const int row = qr[q] + ar0 + m * 16 + ri + i;
          lds[row * 256 + ((g8 ^ (row & 7)) << 3) + c7] =
              f2bf(acc[q][m][n][i] + bv);
        }
    }
  }
  __syncthreads();
#pragma unroll
  for (int jj = 0; jj < 16; ++jj) {
    int c = jj * 512 + tid;
    int row = c >> 5;
    int slot = c & 31;
    u16x8 v = *(const u16x8*)&lds[row * 256 + ((slot ^ (row & 7)) << 3)];
    *(u16x8*)&ob[(size_t)(m0 + row) * ld + ncof + slot * 8] = v;
  }
}

// ============== 128x128 GEMM (small grids: G4, G5) — R6-proven ==============
template <int EPI>
__global__ __launch_bounds__(256, 2) void gemm_bt(
    const unsigned short* __restrict__ A, int lda,
    const unsigned short* __restrict__ W, int ldw,
    const float* __restrict__ bias, int K, int ntx,
    unsigned short* __restrict__ outb, int ldob,
    float* __restrict__ outf,
    const float* __restrict__ hp,
    const unsigned short* __restrict__ scb) {
  __shared__ unsigned short As[2][128 * 64];
  __shared__ unsigned short Ws[2][128 * 64];
  const int tid = threadIdx.x;
  const int lane = tid & 63;
  const int wave = tid >> 6;

  const int nwg = gridDim.x;
  const int cpx = nwg >> 3;
  const int bid = blockIdx.x;
  const int id = (bid & 7) * cpx + (bid >> 3);
  const int bx = id % ntx;
  const int by = id / ntx;

  const int m0 = by * 128;
  const int n0 = bx * 128;
  const int wm = (wave >> 1) * 64;
  const int wn = (wave & 1) * 64;

  f32x4 acc[4][4] = {};

  const int srow = tid >> 3;
  const int sslot = (tid & 7) ^ (srow & 7);
  const unsigned short* Ag = A + (size_t)(m0 + srow) * lda + sslot * 8;
  const unsigned short* Wg = W + (size_t)(n0 + srow) * ldw + sslot * 8;
  unsigned short* Asd = &As[0][tid * 8];
  unsigned short* Wsd = &Ws[0][tid * 8];

  auto stage = [&](int buf, int k0) {
#pragma unroll
    for (int i = 0; i < 4; ++i) {
      gl_lds16(Ag + (size_t)(i * 32) * lda + k0, Asd + buf * 8192 + i * 2048);
      gl_lds16(Wg + (size_t)(i * 32) * ldw + k0, Wsd + buf * 8192 + i * 2048);
    }
  };

  stage(0, 0);
  int cur = 0;
  const int lrow = lane & 15;
  const int kq = (lane >> 4) * 8;
  const int sw = (lrow & 7) << 3;

  for (int k0 = 0; k0 < K; k0 += 64) {
    if (k0 + 64 < K) {
      stage(cur ^ 1, k0 + 64);
      asm volatile("s_waitcnt vmcnt(8)" ::: "memory");
    } else {
      asm volatile("s_waitcnt vmcnt(0)" ::: "memory");
    }
    __builtin_amdgcn_s_barrier();
#pragma unroll
    for (int kk = 0; kk < 2; ++kk) {
      const int kr = kk * 32 + kq;
      const int ki = kr ^ sw;
      bf16x8 af[4], wf[4];
#pragma unroll
      for (int m = 0; m < 4; ++m)
        af[m] = *(const bf16x8*)&As[cur][(wm + m * 16 + lrow) * 64 + ki];
#pragma unroll
      for (int n = 0; n < 4; ++n)
        wf[n] = *(const bf16x8*)&Ws[cur][(wn + n * 16 + lrow) * 64 + ki];
#pragma unroll
      for (int m = 0; m < 4; ++m)
#pragma unroll
        for (int n = 0; n < 4; ++n)
          acc[m][n] = __builtin_amdgcn_mfma_f32_16x16x32_bf16(af[m], wf[n],
                                                              acc[m][n], 0, 0, 0);
    }
    __builtin_amdgcn_s_barrier();
    cur ^= 1;
  }

  if constexpr (EPI == 1) {
    const int r0 = m0 + wm + ((lane >> 4) << 2);
    const int c0 = n0 + wn + lrow;
#pragma unroll
    for (int n = 0; n < 4; ++n) {
      const int col = c0 + n * 16;
      const float bv = bias ? bias[col] : 0.0f;
#pragma unroll
      for (int m = 0; m < 4; ++m) {
#pragma unroll
        for (int i = 0; i < 4; ++i) {
          const int row = r0 + m * 16 + i;
          float g = sigmoidf_(acc[m][n][i] + bv);
          float sc = bf2f(scb[(size_t)row * 1536 + col]);
          float e = hp[(size_t)row * 512 + col] + g * sc;
          outf[(size_t)row * 512 + col] = e;
          outb[(size_t)row * 512 + col] = f2bf(e);
        }
      }
    }
  } else {
    unsigned short* Cs = &As[0][0];
    const int r0l = wm + ((lane >> 4) << 2);
    const int c0l = wn + lrow;
#pragma unroll
    for (int n = 0; n < 4; ++n) {
      const int col = c0l + n * 16;
      const float bv = bias ? bias[n0 + col] : 0.0f;
#pragma unroll
      for (int m = 0; m < 4; ++m)
#pragma unroll
        for (int i = 0; i < 4; ++i)
          Cs[(r0l + m * 16 + i) * 128 + col] = f2bf(acc[m][n][i] + bv);
    }
    __syncthreads();
#pragma unroll
    for (int jj = 0; jj < 8; ++jj) {
      int c = jj * 256 + tid;
      int row = c >> 4;
      int slot = c & 15;
      u16x8 v = *(const u16x8*)&Cs[row * 128 + slot * 8];
      *(u16x8*)&outb[(size_t)(m0 + row) * ldob + n0 + slot * 8] = v;
    }
  }
}

// ---------------- attention over the 2 neighbor states ----------------
__global__ void attn_fuse(const unsigned short* __restrict__ qkvl,
                          const unsigned short* __restrict__ qkvu,
                          unsigned short* __restrict__ ctx) {
  int t = blockIdx.x * blockDim.x + threadIdx.x;
  int g = t >> 4;
  int l = t & 15;
  int b = g >> 2, h = g & 3;
  const size_t base = (size_t)b * 1536 + h * 128 + l * 8;
  u16x8 q0 = *(const u16x8*)(qkvl + base);
  u16x8 k0 = *(const u16x8*)(qkvl + base + 512);
  u16x8 v0 = *(const u16x8*)(qkvl + base + 1024);
  u16x8 q1 = *(const u16x8*)(qkvu + base);
  u16x8 k1 = *(const u16x8*)(qkvu + base + 512);
  u16x8 v1 = *(const u16x8*)(qkvu + base + 1024);
  float s00 = 0.f, s01 = 0.f, s10 = 0.f, s11 = 0.f;
  float v0f[8], v1f[8];
#pragma unroll
  for (int i = 0; i < 8; ++i) {
    float q0f = bf2f(q0[i]), q1f = bf2f(q1[i]);
    float k0f = bf2f(k0[i]), k1f = bf2f(k1[i]);
    v0f[i] = bf2f(v0[i]); v1f[i] = bf2f(v1[i]);
    s00 += q0f * k0f; s01 += q0f * k1f;
    s10 += q1f * k0f; s11 += q1f * k1f;
  }
#pragma unroll
  for (int off = 1; off < 16; off <<= 1) {
    s00 += __shfl_xor(s00, off);
    s01 += __shfl_xor(s01, off);
    s10 += __shfl_xor(s10, off);
    s11 += __shfl_xor(s11, off);
  }
  const float scale = 0.0883883476483184f;
  s00 *= scale; s01 *= scale; s10 *= scale; s11 *= scale;
  float m0 = fmaxf(s00, s01), m1 = fmaxf(s10, s11);
  float a00 = __expf(s00 - m0), a01 = __expf(s01 - m0);
  float a10 = __expf(s10 - m1), a11 = __expf(s11 - m1);
  float c0 = 0.5f * (a00 / (a00 + a01) + a10 / (a10 + a11));
  float c1 = 0.5f * (a01 / (a00 + a01) + a11 / (a10 + a11));
  u16x8 o;
#pragma unroll
  for (int i = 0; i < 8; ++i) o[i] = f2bf(c0 * v0f[i] + c1 * v1f[i]);
  *(u16x8*)(ctx + (size_t)b * 512 + h * 128 + l * 8) = o;
}

// ---------------- GRU elementwise finish ----------------
__global__ void gru_final(const unsigned short* __restrict__ gi,
                          const unsigned short* __restrict__ gh,
                          const float* __restrict__ enh,
                          float* __restrict__ out) {
  int t = blockIdx.x * blockDim.x + threadIdx.x;
  int b = t >> 6;
  int j = (t & 63) * 8;
  size_t gb = (size_t)b * 1536 + j;
  u16x8 ir = *(const u16x8*)(gi + gb);
  u16x8 iz = *(const u16x8*)(gi + gb + 512);
  u16x8 in_ = *(const u16x8*)(gi + gb + 1024);
  u16x8 hr = *(const u16x8*)(gh + gb);
  u16x8 hz = *(const u16x8*)(gh + gb + 512);
  u16x8 hn = *(const u16x8*)(gh + gb + 1024);
  size_t eb = (size_t)b * 512 + j;
  float4 e0 = *(const float4*)(enh + eb);
  float4 e1 = *(const float4*)(enh + eb + 4);
  float ef[8] = {e0.x, e0.y, e0.z, e0.w, e1.x, e1.y, e1.z, e1.w};
  float of[8];
#pragma unroll
  for (int i = 0; i < 8; ++i) {
    float r = sigmoidf_(bf2f(ir[i]) + bf2f(hr[i]));
    float z = sigmoidf_(bf2f(iz[i]) + bf2f(hz[i]));
    float n = tanhf(bf2f(in_[i]) + r * bf2f(hn[i]));
    of[i] = (1.0f - z) * n + z * ef[i];
  }
  *(float4*)(out + eb) = make_float4(of[0], of[1], of[2], of[3]);
  *(float4*)(out + eb + 4) = make_float4(of[4], of[5], of[6], of[7]);
}

extern "C" void kernel_launch(void* const* d_in, const int* in_sizes, int n_in,
                              void* d_out, int out_size, void* d_ws, size_t ws_size,
                              hipStream_t stream) {
  const float* x = (const float*)d_in[0];
  const float* hl = (const float*)d_in[1];
  const float* hu = (const float*)d_in[2];
  const float* hp = (const float*)d_in[3];
  const float* W_in = (const float*)d_in[4];
  const float* b_in = (const float*)d_in[5];
  const float* attn_in_w = (const float*)d_in[6];
  const float* attn_in_b = (const float*)d_in[7];
  const float* attn_out_w = (const float*)d_in[8];
  const float* attn_out_b = (const float*)d_in[9];
  const float* W_gate = (const float*)d_in[10];
  const float* b_gate = (const float*)d_in[11];
  const float* gru_w_ih = (const float*)d_in[12];
  const float* gru_w_hh = (const float*)d_in[13];
  const float* gru_b_ih = (const float*)d_in[14];
  const float* gru_b_hh = (const float*)d_in[15];

  char* ws = (char*)d_ws;
  size_t off = 0;
  auto alloc = [&](size_t bytes) {
    void* p = ws + off;
    off += (bytes + 255) & ~(size_t)255;
    return p;
  };
  unsigned short* wComb = (unsigned short*)alloc((size_t)2048 * 128 * 2);
  unsigned short* wAin  = (unsigned short*)alloc((size_t)1536 * 512 * 2);
  unsigned short* wAout = (unsigned short*)alloc((size_t)512 * 512 * 2);
  unsigned short* wGate = (unsigned short*)alloc((size_t)512 * 1536 * 2);
  unsigned short* wHh   = (unsigned short*)alloc((size_t)1536 * 512 * 2);
  unsigned short* xb   = (unsigned short*)alloc((size_t)NB * 128 * 2);
  unsigned short* hlub = (unsigned short*)alloc((size_t)2 * NB * 512 * 2);
  unsigned short* gate_in = (unsigned short*)alloc((size_t)NB * 1536 * 2);
  unsigned short* qkvb = (unsigned short*)alloc((size_t)2 * NB * 1536 * 2);
  unsigned short* ctxb = (unsigned short*)alloc((size_t)NB * 512 * 2);
  float* enhf = (float*)alloc((size_t)NB * 512 * 4);
  unsigned short* enhb = (unsigned short*)alloc((size_t)NB * 512 * 2);
  unsigned short* qkvl = qkvb;
  unsigned short* qkvu = qkvb + (size_t)NB * 1536;
  unsigned short* gi = qkvl;
  unsigned short* gh = qkvu;

  (void)ws_size; (void)in_sizes; (void)n_in; (void)out_size;

  const int T = 256;

  CvtJobs jobs;
  jobs.src[0] = W_in;       jobs.dst[0] = wComb;
  jobs.src[1] = gru_w_ih;   jobs.dst[1] = wComb + (size_t)512 * 128;
  jobs.src[2] = attn_in_w;  jobs.dst[2] = wAin;
  jobs.src[3] = attn_out_w; jobs.dst[3] = wAout;
  jobs.src[4] = W_gate;     jobs.dst[4] = wGate;
  jobs.src[5] = gru_w_hh;   jobs.dst[5] = wHh;
  jobs.src[6] = x;          jobs.dst[6] = xb;
  jobs.src[7] = hl;         jobs.dst[7] = hlub;
  jobs.src[8] = hu;         jobs.dst[8] = hlub + (size_t)NB * 512;
  cvt_multi<<<(CT + T - 1) / T, T, 0, stream>>>(jobs);
  pack_hp<<<NB * 64 / T, T, 0, stream>>>(hp, gate_in);

  const int MTB = NB / 256;
  const int MTS = NB / 128;

  // G2 batched: qkv for [hl;hu]
  gemm_big<0><<<6 * 2 * MTB, dim3(512), 0, stream>>>(hlub, 512, wAin, 512,
                                                     attn_in_b, nullptr, 512, 6,
                                                     qkvb, 1536, nullptr, 0);
  attn_fuse<<<NB * NHEADS * 16 / T, T, 0, stream>>>(qkvl, qkvu, ctxb);
  // G4
  gemm_bt<0><<<4 * MTS, T, 0, stream>>>(ctxb, 512, wAout, 512, attn_out_b,
                                        512, 4,
                                        gate_in + 512, 1536,
                                        nullptr, nullptr, nullptr);
  // G1+G6 fused
  gemm_big<2><<<8 * MTB, dim3(512), 0, stream>>>(xb, 128, wComb, 128,
                                                 b_in, gru_b_ih, 128, 8,
                                                 gate_in + 1024, 1536, gi, 1536);
  // G5
  gemm_bt<1><<<4 * MTS, T, 0, stream>>>(gate_in, 1536, wGate, 1536, b_gate,
                                        1536, 4,
                                        enhb, 512,
                                        enhf, hp, gate_in + 512);
  // G7
  gemm_big<0><<<6 * MTB, dim3(512), 0, stream>>>(enhb, 512, wHh, 512,
                                                 gru_b_hh, nullptr, 512, 6,
                                                 gh, 1536, nullptr, 0);
  gru_final<<<NB * 64 / T, T, 0, stream>>>(gi, gh, enhf, (float*)d_out);
}

// Round 11
// 280.582 us; speedup vs baseline: 1.4581x; 1.0680x over previous
//
#include <hip/hip_runtime.h>
#include <hip/hip_bf16.h>
#include <stdint.h>

// ImprovedLatticeRNNCell, round 11.
// R10 GEMM structures unchanged (proven). Traffic cuts only:
//  - G5 epilogue reads hp/sc as bf16 from gate_in, writes enhb only
//    (drops 32MB f32 hp read + 32MB enhf write).
//  - gru_final reads enhb (16MB) instead of enhf (32MB).

#define NB 16384
#define NHEADS 4

typedef __attribute__((ext_vector_type(8))) __bf16 bf16x8;
typedef __attribute__((ext_vector_type(4))) float f32x4;
typedef __attribute__((ext_vector_type(8))) unsigned short u16x8;

__device__ __forceinline__ unsigned short f2bf(float f) {
  union { float f; unsigned int u; } v; v.f = f;
  unsigned int u = v.u;
  unsigned int r = (u + 0x7fffu + ((u >> 16) & 1u)) >> 16;
  return (unsigned short)r;
}
__device__ __forceinline__ float bf2f(unsigned short h) {
  union { unsigned int u; float f; } v; v.u = ((unsigned int)h) << 16;
  return v.f;
}
__device__ __forceinline__ float sigmoidf_(float x) {
  return 1.0f / (1.0f + __expf(-x));
}

// ---------------- merged f32 -> bf16 conversion (9 jobs, 1 launch) ----------
#define J0 (512 * 128 / 8)
#define J1 (1536 * 128 / 8)
#define J2 (1536 * 512 / 8)
#define J3 (512 * 512 / 8)
#define J4 (512 * 1536 / 8)
#define J5 (1536 * 512 / 8)
#define J6 (NB * 128 / 8)
#define J7 (NB * 512 / 8)
#define J8 (NB * 512 / 8)
#define C1 (J0)
#define C2 (C1 + J1)
#define C3 (C2 + J2)
#define C4 (C3 + J3)
#define C5 (C4 + J4)
#define C6 (C5 + J5)
#define C7 (C6 + J6)
#define C8 (C7 + J7)
#define CT (C8 + J8)

struct CvtJobs {
  const float* src[9];
  unsigned short* dst[9];
};

__global__ void cvt_multi(CvtJobs j) {
  int g = blockIdx.x * blockDim.x + threadIdx.x;
  if (g >= CT) return;
  int k, base;
  if (g < C4) {
    if (g < C2) {
      if (g < C1) { k = 0; base = 0; } else { k = 1; base = C1; }
    } else {
      if (g < C3) { k = 2; base = C2; } else { k = 3; base = C3; }
    }
  } else {
    if (g < C6) {
      if (g < C5) { k = 4; base = C4; } else { k = 5; base = C5; }
    } else {
      if (g < C7) { k = 6; base = C6; }
      else if (g < C8) { k = 7; base = C7; }
      else { k = 8; base = C8; }
    }
  }
  int local = g - base;
  const float4* s = (const float4*)j.src[k] + (size_t)local * 2;
  float4 a = s[0], b = s[1];
  u16x8 o;
  o[0] = f2bf(a.x); o[1] = f2bf(a.y); o[2] = f2bf(a.z); o[3] = f2bf(a.w);
  o[4] = f2bf(b.x); o[5] = f2bf(b.y); o[6] = f2bf(b.z); o[7] = f2bf(b.w);
  *((u16x8*)j.dst[k] + local) = o;
}

__global__ void pack_hp(const float* __restrict__ hp,
                        unsigned short* __restrict__ gate_in) {
  int t = blockIdx.x * blockDim.x + threadIdx.x;
  int b = t >> 6;
  int j = (t & 63) * 8;
  const float4* s = (const float4*)(hp + (size_t)b * 512 + j);
  float4 a = s[0], c = s[1];
  u16x8 o;
  o[0] = f2bf(a.x); o[1] = f2bf(a.y); o[2] = f2bf(a.z); o[3] = f2bf(a.w);
  o[4] = f2bf(c.x); o[5] = f2bf(c.y); o[6] = f2bf(c.z); o[7] = f2bf(c.w);
  *(u16x8*)(gate_in + (size_t)b * 1536 + j) = o;
}

__device__ __forceinline__ void gl_lds16(const unsigned short* g, unsigned short* l) {
  __builtin_amdgcn_global_load_lds(
      (const __attribute__((address_space(1))) void*)g,
      (__attribute__((address_space(3))) void*)l, 16, 0, 0);
}

// ============== 256x256 GEMM, 4-phase quadrant schedule (R10-proven) =========
template <int EPI>
__global__ __launch_bounds__(512, 1) void gemm_big(
    const unsigned short* __restrict__ A, int lda,
    const unsigned short* __restrict__ W, int ldw,
    const float* __restrict__ bias, const float* __restrict__ bias2,
    int K, int ntx,
    unsigned short* __restrict__ outb, int ldob,
    unsigned short* __restrict__ outb2, int ldob2) {
  __shared__ unsigned short lds[65536];
  unsigned short* Asb = lds;
  unsigned short* Bsb = lds + 32768;
  const int tid = threadIdx.x;
  const int lane = tid & 63;
  const int wave = tid >> 6;

  const int nwg = gridDim.x;
  const int cpx = nwg >> 3;
  const int bid = blockIdx.x;
  const int id = (bid & 7) * cpx + (bid >> 3);
  const int bx = id % ntx;
  const int by = id / ntx;

  const int m0 = by * 256;
  const int n0 = bx * 256;
  const int ar0 = (wave >> 2) * 64;
  const int br0 = (wave & 3) * 32;

  f32x4 acc[4][4][2] = {};

  const int srow = tid >> 3;
  const int presw = (tid & 7) ^ (srow & 7);
  const unsigned short* Ag = A + (size_t)(m0 + srow) * lda + presw * 8;
  const unsigned short* Wg = W + (size_t)(n0 + srow) * ldw + presw * 8;
  unsigned short* Asd = Asb + tid * 8;
  unsigned short* Wsd = Bsb + tid * 8;

  auto stageA = [&](int buf, int h, int k0) {
    const unsigned short* s = Ag + (size_t)(h * 128) * lda + k0;
    unsigned short* d = Asd + buf * 16384 + h * 8192;
    gl_lds16(s, d);
    gl_lds16(s + (size_t)64 * lda, d + 4096);
  };
  auto stageB = [&](int buf, int h, int k0) {
    const unsigned short* s = Wg + (size_t)(h * 128) * ldw + k0;
    unsigned short* d = Wsd + buf * 16384 + h * 8192;
    gl_lds16(s, d);
    gl_lds16(s + (size_t)64 * ldw, d + 4096);
  };

  const int lrow = lane & 15;
  const int kq = (lane >> 4) * 8;
  const int sw = (lrow & 7) << 3;
  const int NT = K >> 6;

  stageA(0, 0, 0);
  stageB(0, 0, 0);
  stageB(0, 1, 0);
  stageA(0, 1, 0);
  asm volatile("s_waitcnt vmcnt(4)" ::: "memory");
  __builtin_amdgcn_s_barrier();

  bf16x8 a[4][2], b0[2][2], b1[2][2];

#define RD_A(X, H)                                                            \
  _Pragma("unroll") for (int m = 0; m < 4; ++m)                               \
  _Pragma("unroll") for (int kk = 0; kk < 2; ++kk)                            \
      a[m][kk] = *(const bf16x8*)&Asb[(X) * 16384 +                           \
                                      ((H) * 128 + ar0 + m * 16 + lrow) * 64 +\
                                      ((kk * 32 + kq) ^ sw)];
#define RD_B(X, H, DST)                                                       \
  _Pragma("unroll") for (int n = 0; n < 2; ++n)                               \
  _Pragma("unroll") for (int kk = 0; kk < 2; ++kk)                            \
      DST[n][kk] = *(const bf16x8*)&Bsb[(X) * 16384 +                         \
                                        ((H) * 128 + br0 + n * 16 + lrow) * 64 + \
                                        ((kk * 32 + kq) ^ sw)];
#define MFMA_Q(Q, BF)                                                         \
  __builtin_amdgcn_s_setprio(1);                                              \
  _Pragma("unroll") for (int m = 0; m < 4; ++m)                               \
  _Pragma("unroll") for (int n = 0; n < 2; ++n)                               \
  _Pragma("unroll") for (int kk = 0; kk < 2; ++kk)                            \
      acc[Q][m][n] = __builtin_amdgcn_mfma_f32_16x16x32_bf16(                 \
          a[m][kk], BF[n][kk], acc[Q][m][n], 0, 0, 0);                        \
  __builtin_amdgcn_s_setprio(0);
#define LGKM0                                                                 \
  asm volatile("s_waitcnt lgkmcnt(0)" ::: "memory");                          \
  __builtin_amdgcn_sched_barrier(0);
#define BAR __builtin_amdgcn_s_barrier();

  for (int t = 0; t < NT - 1; ++t) {
    const int X = t & 1, Y = X ^ 1;
    const int kn = (t + 1) << 6;
    RD_A(X, 0)
    RD_B(X, 0, b0)
    stageA(Y, 0, kn);
    stageB(Y, 0, kn);
    asm volatile("s_waitcnt vmcnt(4)" ::: "memory");
    BAR LGKM0
    MFMA_Q(0, b0)
    BAR
    RD_B(X, 1, b1)
    stageB(Y, 1, kn);
    BAR LGKM0
    MFMA_Q(1, b1)
    BAR
    RD_A(X, 1)
    stageA(Y, 1, kn);
    BAR LGKM0
    MFMA_Q(2, b1)
    BAR
    asm volatile("s_waitcnt vmcnt(4)" ::: "memory");
    BAR
    __builtin_amdgcn_sched_barrier(0);
    MFMA_Q(3, b0)
    BAR
  }
  {
    const int X = (NT - 1) & 1;
    RD_A(X, 0)
    RD_B(X, 0, b0)
    asm volatile("s_waitcnt vmcnt(0)" ::: "memory");
    BAR LGKM0
    MFMA_Q(0, b0)
    RD_B(X, 1, b1)
    LGKM0
    MFMA_Q(1, b1)
    RD_A(X, 1)
    LGKM0
    MFMA_Q(2, b1)
    MFMA_Q(3, b0)
  }
#undef RD_A
#undef RD_B
#undef MFMA_Q
#undef LGKM0
#undef BAR

  __syncthreads();
  unsigned short* ob = outb;
  int ld = ldob, ncof = n0;
  const float* bp = bias;
  if constexpr (EPI == 2) {
    if (n0 >= 512) { ob = outb2; ld = ldob2; ncof = n0 - 512; bp = bias2; }
  }
  const int qr[4] = {0, 0, 128, 128};
  const int qc[4] = {0, 128, 128, 0};
  const int ri = (lane >> 4) << 2;
#pragma unroll
  for (int q = 0; q < 4; ++q) {
#pragma unroll
    for (int n = 0; n < 2; ++n) {
      const int col = qc[q] + br0 + n * 16 + lrow;
      const float bv = bp ? bp[ncof + col] : 0.0f;
      const int g8 = col >> 3, c7 = col & 7;
#pragma unroll
      for (int m = 0; m < 4; ++m)
#pragma unroll
        for (int i = 0; i < 4; ++i) {
          const int row = qr[q] + ar0 + m * 16 + ri + i;
          lds[row * 256 + ((g8 ^ (row & 7)) << 3) + c7] =
              f2bf(acc[q][m][n][i] + bv);
        }
    }
  }
  __syncthreads();
#pragma unroll
  for (int jj = 0; jj < 16; ++jj) {
    int c = jj * 512 + tid;
    int row = c >> 5;
    int slot = c & 31;
    u16x8 v = *(const u16x8*)&lds[row * 256 + ((slot ^ (row & 7)) << 3)];
    *(u16x8*)&ob[(size_t)(m0 + row) * ld + ncof + slot * 8] = v;
  }
}

// ============== 128x128 GEMM (small grids: G4, G5) — R6-proven ==============
// EPI 0: plain bf16 out (coalesced LDS epilogue)
// EPI 1: gate epilogue: hp/sc read as bf16 from gin ([B,1536]: hp|sc|xp);
//        writes enhb (bf16) only.
template <int EPI>
__global__ __launch_bounds__(256, 2) void gemm_bt(
    const unsigned short* __restrict__ A, int lda,
    const unsigned short* __restrict__ W, int ldw,
    const float* __restrict__ bias, int K, int ntx,
    unsigned short* __restrict__ outb, int ldob,
    const unsigned short* __restrict__ gin) {
  __shared__ unsigned short As[2][128 * 64];
  __shared__ unsigned short Ws[2][128 * 64];
  const int tid = threadIdx.x;
  const int lane = tid & 63;
  const int wave = tid >> 6;

  const int nwg = gridDim.x;
  const int cpx = nwg >> 3;
  const int bid = blockIdx.x;
  const int id = (bid & 7) * cpx + (bid >> 3);
  const int bx = id % ntx;
  const int by = id / ntx;

  const int m0 = by * 128;
  const int n0 = bx * 128;
  const int wm = (wave >> 1) * 64;
  const int wn = (wave & 1) * 64;

  f32x4 acc[4][4] = {};

  const int srow = tid >> 3;
  const int sslot = (tid & 7) ^ (srow & 7);
  const unsigned short* Ag = A + (size_t)(m0 + srow) * lda + sslot * 8;
  const unsigned short* Wg = W + (size_t)(n0 + srow) * ldw + sslot * 8;
  unsigned short* Asd = &As[0][tid * 8];
  unsigned short* Wsd = &Ws[0][tid * 8];

  auto stage = [&](int buf, int k0) {
#pragma unroll
    for (int i = 0; i < 4; ++i) {
      gl_lds16(Ag + (size_t)(i * 32) * lda + k0, Asd + buf * 8192 + i * 2048);
      gl_lds16(Wg + (size_t)(i * 32) * ldw + k0, Wsd + buf * 8192 + i * 2048);
    }
  };

  stage(0, 0);
  int cur = 0;
  const int lrow = lane & 15;
  const int kq = (lane >> 4) * 8;
  const int sw = (lrow & 7) << 3;

  for (int k0 = 0; k0 < K; k0 += 64) {
    if (k0 + 64 < K) {
      stage(cur ^ 1, k0 + 64);
      asm volatile("s_waitcnt vmcnt(8)" ::: "memory");
    } else {
      asm volatile("s_waitcnt vmcnt(0)" ::: "memory");
    }
    __builtin_amdgcn_s_barrier();
#pragma unroll
    for (int kk = 0; kk < 2; ++kk) {
      const int kr = kk * 32 + kq;
      const int ki = kr ^ sw;
      bf16x8 af[4], wf[4];
#pragma unroll
      for (int m = 0; m < 4; ++m)
        af[m] = *(const bf16x8*)&As[cur][(wm + m * 16 + lrow) * 64 + ki];
#pragma unroll
      for (int n = 0; n < 4; ++n)
        wf[n] = *(const bf16x8*)&Ws[cur][(wn + n * 16 + lrow) * 64 + ki];
#pragma unroll
      for (int m = 0; m < 4; ++m)
#pragma unroll
        for (int n = 0; n < 4; ++n)
          acc[m][n] = __builtin_amdgcn_mfma_f32_16x16x32_bf16(af[m], wf[n],
                                                              acc[m][n], 0, 0, 0);
    }
    __builtin_amdgcn_s_barrier();
    cur ^= 1;
  }

  if constexpr (EPI == 1) {
    // gate epilogue: g = sigmoid(acc + bias); enhanced = hp + g*sc
    // hp = gin[row][col], sc = gin[row][512+col]  (bf16)
    const int r0 = m0 + wm + ((lane >> 4) << 2);
    const int c0 = n0 + wn + lrow;
#pragma unroll
    for (int n = 0; n < 4; ++n) {
      const int col = c0 + n * 16;
      const float bv = bias ? bias[col] : 0.0f;
#pragma unroll
      for (int m = 0; m < 4; ++m) {
#pragma unroll
        for (int i = 0; i < 4; ++i) {
          const int row = r0 + m * 16 + i;
          float g = sigmoidf_(acc[m][n][i] + bv);
          float hpv = bf2f(gin[(size_t)row * 1536 + col]);
          float sc = bf2f(gin[(size_t)row * 1536 + 512 + col]);
          float e = hpv + g * sc;
          outb[(size_t)row * 512 + col] = f2bf(e);
        }
      }
    }
  } else {
    unsigned short* Cs = &As[0][0];
    const int r0l = wm + ((lane >> 4) << 2);
    const int c0l = wn + lrow;
#pragma unroll
    for (int n = 0; n < 4; ++n) {
      const int col = c0l + n * 16;
      const float bv = bias ? bias[n0 + col] : 0.0f;
#pragma unroll
      for (int m = 0; m < 4; ++m)
#pragma unroll
        for (int i = 0; i < 4; ++i)
          Cs[(r0l + m * 16 + i) * 128 + col] = f2bf(acc[m][n][i] + bv);
    }
    __syncthreads();
#pragma unroll
    for (int jj = 0; jj < 8; ++jj) {
      int c = jj * 256 + tid;
      int row = c >> 4;
      int slot = c & 15;
      u16x8 v = *(const u16x8*)&Cs[row * 128 + slot * 8];
      *(u16x8*)&outb[(size_t)(m0 + row) * ldob + n0 + slot * 8] = v;
    }
  }
}

// ---------------- attention over the 2 neighbor states ----------------
__global__ void attn_fuse(const unsigned short* __restrict__ qkvl,
                          const unsigned short* __restrict__ qkvu,
                          unsigned short* __restrict__ ctx) {
  int t = blockIdx.x * blockDim.x + threadIdx.x;
  int g = t >> 4;
  int l = t & 15;
  int b = g >> 2, h = g & 3;
  const size_t base = (size_t)b * 1536 + h * 128 + l * 8;
  u16x8 q0 = *(const u16x8*)(qkvl + base);
  u16x8 k0 = *(const u16x8*)(qkvl + base + 512);
  u16x8 v0 = *(const u16x8*)(qkvl + base + 1024);
  u16x8 q1 = *(const u16x8*)(qkvu + base);
  u16x8 k1 = *(const u16x8*)(qkvu + base + 512);
  u16x8 v1 = *(const u16x8*)(qkvu + base + 1024);
  float s00 = 0.f, s01 = 0.f, s10 = 0.f, s11 = 0.f;
  float v0f[8], v1f[8];
#pragma unroll
  for (int i = 0; i < 8; ++i) {
    float q0f = bf2f(q0[i]), q1f = bf2f(q1[i]);
    float k0f = bf2f(k0[i]), k1f = bf2f(k1[i]);
    v0f[i] = bf2f(v0[i]); v1f[i] = bf2f(v1[i]);
    s00 += q0f * k0f; s01 += q0f * k1f;
    s10 += q1f * k0f; s11 += q1f * k1f;
  }
#pragma unroll
  for (int off = 1; off < 16; off <<= 1) {
    s00 += __shfl_xor(s00, off);
    s01 += __shfl_xor(s01, off);
    s10 += __shfl_xor(s10, off);
    s11 += __shfl_xor(s11, off);
  }
  const float scale = 0.0883883476483184f;
  s00 *= scale; s01 *= scale; s10 *= scale; s11 *= scale;
  float m0 = fmaxf(s00, s01), m1 = fmaxf(s10, s11);
  float a00 = __expf(s00 - m0), a01 = __expf(s01 - m0);
  float a10 = __expf(s10 - m1), a11 = __expf(s11 - m1);
  float c0 = 0.5f * (a00 / (a00 + a01) + a10 / (a10 + a11));
  float c1 = 0.5f * (a01 / (a00 + a01) + a11 / (a10 + a11));
  u16x8 o;
#pragma unroll
  for (int i = 0; i < 8; ++i) o[i] = f2bf(c0 * v0f[i] + c1 * v1f[i]);
  *(u16x8*)(ctx + (size_t)b * 512 + h * 128 + l * 8) = o;
}

// ---------------- GRU elementwise finish (enh in bf16) ----------------
__global__ void gru_final(const unsigned short* __restrict__ gi,
                          const unsigned short* __restrict__ gh,
                          const unsigned short* __restrict__ enh,
                          float* __restrict__ out) {
  int t = blockIdx.x * blockDim.x + threadIdx.x;
  int b = t >> 6;
  int j = (t & 63) * 8;
  size_t gb = (size_t)b * 1536 + j;
  u16x8 ir = *(const u16x8*)(gi + gb);
  u16x8 iz = *(const u16x8*)(gi + gb + 512);
  u16x8 in_ = *(const u16x8*)(gi + gb + 1024);
  u16x8 hr = *(const u16x8*)(gh + gb);
  u16x8 hz = *(const u16x8*)(gh + gb + 512);
  u16x8 hn = *(const u16x8*)(gh + gb + 1024);
  size_t eb = (size_t)b * 512 + j;
  u16x8 ev = *(const u16x8*)(enh + eb);
  float of[8];
#pragma unroll
  for (int i = 0; i < 8; ++i) {
    float r = sigmoidf_(bf2f(ir[i]) + bf2f(hr[i]));
    float z = sigmoidf_(bf2f(iz[i]) + bf2f(hz[i]));
    float n = tanhf(bf2f(in_[i]) + r * bf2f(hn[i]));
    of[i] = (1.0f - z) * n + z * bf2f(ev[i]);
  }
  *(float4*)(out + eb) = make_float4(of[0], of[1], of[2], of[3]);
  *(float4*)(out + eb + 4) = make_float4(of[4], of[5], of[6], of[7]);
}

extern "C" void kernel_launch(void* const* d_in, const int* in_sizes, int n_in,
                              void* d_out, int out_size, void* d_ws, size_t ws_size,
                              hipStream_t stream) {
  const float* x = (const float*)d_in[0];
  const float* hl = (const float*)d_in[1];
  const float* hu = (const float*)d_in[2];
  const float* hp = (const float*)d_in[3];
  const float* W_in = (const float*)d_in[4];
  const float* b_in = (const float*)d_in[5];
  const float* attn_in_w = (const float*)d_in[6];
  const float* attn_in_b = (const float*)d_in[7];
  const float* attn_out_w = (const float*)d_in[8];
  const float* attn_out_b = (const float*)d_in[9];
  const float* W_gate = (const float*)d_in[10];
  const float* b_gate = (const float*)d_in[11];
  const float* gru_w_ih = (const float*)d_in[12];
  const float* gru_w_hh = (const float*)d_in[13];
  const float* gru_b_ih = (const float*)d_in[14];
  const float* gru_b_hh = (const float*)d_in[15];

  char* ws = (char*)d_ws;
  size_t off = 0;
  auto alloc = [&](size_t bytes) {
    void* p = ws + off;
    off += (bytes + 255) & ~(size_t)255;
    return p;
  };
  unsigned short* wComb = (unsigned short*)alloc((size_t)2048 * 128 * 2);
  unsigned short* wAin  = (unsigned short*)alloc((size_t)1536 * 512 * 2);
  unsigned short* wAout = (unsigned short*)alloc((size_t)512 * 512 * 2);
  unsigned short* wGate = (unsigned short*)alloc((size_t)512 * 1536 * 2);
  unsigned short* wHh   = (unsigned short*)alloc((size_t)1536 * 512 * 2);
  unsigned short* xb   = (unsigned short*)alloc((size_t)NB * 128 * 2);
  unsigned short* hlub = (unsigned short*)alloc((size_t)2 * NB * 512 * 2);
  unsigned short* gate_in = (unsigned short*)alloc((size_t)NB * 1536 * 2);
  unsigned short* qkvb = (unsigned short*)alloc((size_t)2 * NB * 1536 * 2);
  unsigned short* ctxb = (unsigned short*)alloc((size_t)NB * 512 * 2);
  unsigned short* enhb = (unsigned short*)alloc((size_t)NB * 512 * 2);
  unsigned short* qkvl = qkvb;
  unsigned short* qkvu = qkvb + (size_t)NB * 1536;
  unsigned short* gi = qkvl;
  unsigned short* gh = qkvu;

  (void)ws_size; (void)in_sizes; (void)n_in; (void)out_size;

  const int T = 256;

  CvtJobs jobs;
  jobs.src[0] = W_in;       jobs.dst[0] = wComb;
  jobs.src[1] = gru_w_ih;   jobs.dst[1] = wComb + (size_t)512 * 128;
  jobs.src[2] = attn_in_w;  jobs.dst[2] = wAin;
  jobs.src[3] = attn_out_w; jobs.dst[3] = wAout;
  jobs.src[4] = W_gate;     jobs.dst[4] = wGate;
  jobs.src[5] = gru_w_hh;   jobs.dst[5] = wHh;
  jobs.src[6] = x;          jobs.dst[6] = xb;
  jobs.src[7] = hl;         jobs.dst[7] = hlub;
  jobs.src[8] = hu;         jobs.dst[8] = hlub + (size_t)NB * 512;
  cvt_multi<<<(CT + T - 1) / T, T, 0, stream>>>(jobs);
  pack_hp<<<NB * 64 / T, T, 0, stream>>>(hp, gate_in);

  const int MTB = NB / 256;
  const int MTS = NB / 128;

  // G2 batched: qkv for [hl;hu]
  gemm_big<0><<<6 * 2 * MTB, dim3(512), 0, stream>>>(hlub, 512, wAin, 512,
                                                     attn_in_b, nullptr, 512, 6,
                                                     qkvb, 1536, nullptr, 0);
  attn_fuse<<<NB * NHEADS * 16 / T, T, 0, stream>>>(qkvl, qkvu, ctxb);
  // G4
  gemm_bt<0><<<4 * MTS, T, 0, stream>>>(ctxb, 512, wAout, 512, attn_out_b,
                                        512, 4,
                                        gate_in + 512, 1536, nullptr);
  // G1+G6 fused
  gemm_big<2><<<8 * MTB, dim3(512), 0, stream>>>(xb, 128, wComb, 128,
                                                 b_in, gru_b_ih, 128, 8,
                                                 gate_in + 1024, 1536, gi, 1536);
  // G5: gate + enhanced (hp/sc from gate_in bf16; writes enhb only)
  gemm_bt<1><<<4 * MTS, T, 0, stream>>>(gate_in, 1536, wGate, 1536, b_gate,
                                        1536, 4,
                                        enhb, 512, gate_in);
  // G7
  gemm_big<0><<<6 * MTB, dim3(512), 0, stream>>>(enhb, 512, wHh, 512,
                                                 gru_b_hh, nullptr, 512, 6,
                                                 gh, 1536, nullptr, 0);
  gru_final<<<NB * 64 / T, T, 0, stream>>>(gi, gh, enhb, (float*)d_out);
}

// Round 12
// 271.097 us; speedup vs baseline: 1.5091x; 1.0350x over previous
//
#include <hip/hip_runtime.h>
#include <hip/hip_bf16.h>
#include <stdint.h>

// ImprovedLatticeRNNCell, round 12.
// R11 + fused G7+gru_final ("g7_gru"): BM=128, B panel = 3x128 gate-strips
// of w_hh (no weight permutation), 8 waves (2M x 4J), R8-proven monolithic
// pipeline (8 gloads/stage, vmcnt(8)). GRU computed in-epilogue, writes f32
// output directly; gh never materialized.

#define NB 16384
#define NHEADS 4

typedef __attribute__((ext_vector_type(8))) __bf16 bf16x8;
typedef __attribute__((ext_vector_type(4))) float f32x4;
typedef __attribute__((ext_vector_type(8))) unsigned short u16x8;

__device__ __forceinline__ unsigned short f2bf(float f) {
  union { float f; unsigned int u; } v; v.f = f;
  unsigned int u = v.u;
  unsigned int r = (u + 0x7fffu + ((u >> 16) & 1u)) >> 16;
  return (unsigned short)r;
}
__device__ __forceinline__ float bf2f(unsigned short h) {
  union { unsigned int u; float f; } v; v.u = ((unsigned int)h) << 16;
  return v.f;
}
__device__ __forceinline__ float sigmoidf_(float x) {
  return 1.0f / (1.0f + __expf(-x));
}

// ---------------- merged f32 -> bf16 conversion (9 jobs, 1 launch) ----------
#define J0 (512 * 128 / 8)
#define J1 (1536 * 128 / 8)
#define J2 (1536 * 512 / 8)
#define J3 (512 * 512 / 8)
#define J4 (512 * 1536 / 8)
#define J5 (1536 * 512 / 8)
#define J6 (NB * 128 / 8)
#define J7 (NB * 512 / 8)
#define J8 (NB * 512 / 8)
#define C1 (J0)
#define C2 (C1 + J1)
#define C3 (C2 + J2)
#define C4 (C3 + J3)
#define C5 (C4 + J4)
#define C6 (C5 + J5)
#define C7 (C6 + J6)
#define C8 (C7 + J7)
#define CT (C8 + J8)

struct CvtJobs {
  const float* src[9];
  unsigned short* dst[9];
};

__global__ void cvt_multi(CvtJobs j) {
  int g = blockIdx.x * blockDim.x + threadIdx.x;
  if (g >= CT) return;
  int k, base;
  if (g < C4) {
    if (g < C2) {
      if (g < C1) { k = 0; base = 0; } else { k = 1; base = C1; }
    } else {
      if (g < C3) { k = 2; base = C2; } else { k = 3; base = C3; }
    }
  } else {
    if (g < C6) {
      if (g < C5) { k = 4; base = C4; } else { k = 5; base = C5; }
    } else {
      if (g < C7) { k = 6; base = C6; }
      else if (g < C8) { k = 7; base = C7; }
      else { k = 8; base = C8; }
    }
  }
  int local = g - base;
  const float4* s = (const float4*)j.src[k] + (size_t)local * 2;
  float4 a = s[0], b = s[1];
  u16x8 o;
  o[0] = f2bf(a.x); o[1] = f2bf(a.y); o[2] = f2bf(a.z); o[3] = f2bf(a.w);
  o[4] = f2bf(b.x); o[5] = f2bf(b.y); o[6] = f2bf(b.z); o[7] = f2bf(b.w);
  *((u16x8*)j.dst[k] + local) = o;
}

__global__ void pack_hp(const float* __restrict__ hp,
                        unsigned short* __restrict__ gate_in) {
  int t = blockIdx.x * blockDim.x + threadIdx.x;
  int b = t >> 6;
  int j = (t & 63) * 8;
  const float4* s = (const float4*)(hp + (size_t)b * 512 + j);
  float4 a = s[0], c = s[1];
  u16x8 o;
  o[0] = f2bf(a.x); o[1] = f2bf(a.y); o[2] = f2bf(a.z); o[3] = f2bf(a.w);
  o[4] = f2bf(c.x); o[5] = f2bf(c.y); o[6] = f2bf(c.z); o[7] = f2bf(c.w);
  *(u16x8*)(gate_in + (size_t)b * 1536 + j) = o;
}

__device__ __forceinline__ void gl_lds16(const unsigned short* g, unsigned short* l) {
  __builtin_amdgcn_global_load_lds(
      (const __attribute__((address_space(1))) void*)g,
      (__attribute__((address_space(3))) void*)l, 16, 0, 0);
}

// ============== 256x256 GEMM, 4-phase quadrant schedule (R10-proven) =========
template <int EPI>
__global__ __launch_bounds__(512, 1) void gemm_big(
    const unsigned short* __restrict__ A, int lda,
    const unsigned short* __restrict__ W, int ldw,
    const float* __restrict__ bias, const float* __restrict__ bias2,
    int K, int ntx,
    unsigned short* __restrict__ outb, int ldob,
    unsigned short* __restrict__ outb2, int ldob2) {
  __shared__ unsigned short lds[65536];
  unsigned short* Asb = lds;
  unsigned short* Bsb = lds + 32768;
  const int tid = threadIdx.x;
  const int lane = tid & 63;
  const int wave = tid >> 6;

  const int nwg = gridDim.x;
  const int cpx = nwg >> 3;
  const int bid = blockIdx.x;
  const int id = (bid & 7) * cpx + (bid >> 3);
  const int bx = id % ntx;
  const int by = id / ntx;

  const int m0 = by * 256;
  const int n0 = bx * 256;
  const int ar0 = (wave >> 2) * 64;
  const int br0 = (wave & 3) * 32;

  f32x4 acc[4][4][2] = {};

  const int srow = tid >> 3;
  const int presw = (tid & 7) ^ (srow & 7);
  const unsigned short* Ag = A + (size_t)(m0 + srow) * lda + presw * 8;
  const unsigned short* Wg = W + (size_t)(n0 + srow) * ldw + presw * 8;
  unsigned short* Asd = Asb + tid * 8;
  unsigned short* Wsd = Bsb + tid * 8;

  auto stageA = [&](int buf, int h, int k0) {
    const unsigned short* s = Ag + (size_t)(h * 128) * lda + k0;
    unsigned short* d = Asd + buf * 16384 + h * 8192;
    gl_lds16(s, d);
    gl_lds16(s + (size_t)64 * lda, d + 4096);
  };
  auto stageB = [&](int buf, int h, int k0) {
    const unsigned short* s = Wg + (size_t)(h * 128) * ldw + k0;
    unsigned short* d = Wsd + buf * 16384 + h * 8192;
    gl_lds16(s, d);
    gl_lds16(s + (size_t)64 * ldw, d + 4096);
  };

  const int lrow = lane & 15;
  const int kq = (lane >> 4) * 8;
  const int sw = (lrow & 7) << 3;
  const int NT = K >> 6;

  stageA(0, 0, 0);
  stageB(0, 0, 0);
  stageB(0, 1, 0);
  stageA(0, 1, 0);
  asm volatile("s_waitcnt vmcnt(4)" ::: "memory");
  __builtin_amdgcn_s_barrier();

  bf16x8 a[4][2], b0[2][2], b1[2][2];

#define RD_A(X, H)                                                            \
  _Pragma("unroll") for (int m = 0; m < 4; ++m)                               \
  _Pragma("unroll") for (int kk = 0; kk < 2; ++kk)                            \
      a[m][kk] = *(const bf16x8*)&Asb[(X) * 16384 +                           \
                                      ((H) * 128 + ar0 + m * 16 + lrow) * 64 +\
                                      ((kk * 32 + kq) ^ sw)];
#define RD_B(X, H, DST)                                                       \
  _Pragma("unroll") for (int n = 0; n < 2; ++n)                               \
  _Pragma("unroll") for (int kk = 0; kk < 2; ++kk)                            \
      DST[n][kk] = *(const bf16x8*)&Bsb[(X) * 16384 +                         \
                                        ((H) * 128 + br0 + n * 16 + lrow) * 64 + \
                                        ((kk * 32 + kq) ^ sw)];
#define MFMA_Q(Q, BF)                                                         \
  __builtin_amdgcn_s_setprio(1);                                              \
  _Pragma("unroll") for (int m = 0; m < 4; ++m)                               \
  _Pragma("unroll") for (int n = 0; n < 2; ++n)                               \
  _Pragma("unroll") for (int kk = 0; kk < 2; ++kk)                            \
      acc[Q][m][n] = __builtin_amdgcn_mfma_f32_16x16x32_bf16(                 \
          a[m][kk], BF[n][kk], acc[Q][m][n], 0, 0, 0);                        \
  __builtin_amdgcn_s_setprio(0);
#define LGKM0                                                                 \
  asm volatile("s_waitcnt lgkmcnt(0)" ::: "memory");                          \
  __builtin_amdgcn_sched_barrier(0);
#define BAR __builtin_amdgcn_s_barrier();

  for (int t = 0; t < NT - 1; ++t) {
    const int X = t & 1, Y = X ^ 1;
    const int kn = (t + 1) << 6;
    RD_A(X, 0)
    RD_B(X, 0, b0)
    stageA(Y, 0, kn);
    stageB(Y, 0, kn);
    asm volatile("s_waitcnt vmcnt(4)" ::: "memory");
    BAR LGKM0
    MFMA_Q(0, b0)
    BAR
    RD_B(X, 1, b1)
    stageB(Y, 1, kn);
    BAR LGKM0
    MFMA_Q(1, b1)
    BAR
    RD_A(X, 1)
    stageA(Y, 1, kn);
    BAR LGKM0
    MFMA_Q(2, b1)
    BAR
    asm volatile("s_waitcnt vmcnt(4)" ::: "memory");
    BAR
    __builtin_amdgcn_sched_barrier(0);
    MFMA_Q(3, b0)
    BAR
  }
  {
    const int X = (NT - 1) & 1;
    RD_A(X, 0)
    RD_B(X, 0, b0)
    asm volatile("s_waitcnt vmcnt(0)" ::: "memory");
    BAR LGKM0
    MFMA_Q(0, b0)
    RD_B(X, 1, b1)
    LGKM0
    MFMA_Q(1, b1)
    RD_A(X, 1)
    LGKM0
    MFMA_Q(2, b1)
    MFMA_Q(3, b0)
  }
#undef RD_A
#undef RD_B
#undef MFMA_Q
#undef LGKM0
#undef BAR

  __syncthreads();
  unsigned short* ob = outb;
  int ld = ldob, ncof = n0;
  const float* bp = bias;
  if constexpr (EPI == 2) {
    if (n0 >= 512) { ob = outb2; ld = ldob2; ncof = n0 - 512; bp = bias2; }
  }
  const int qr[4] = {0, 0, 128, 128};
  const int qc[4] = {0, 128, 128, 0};
  const int ri = (lane >> 4) << 2;
#pragma unroll
  for (int q = 0; q < 4; ++q) {
#pragma unroll
    for (int n = 0; n < 2; ++n) {
      const int col = qc[q] + br0 + n * 16 + lrow;
      const float bv = bp ? bp[ncof + col] : 0.0f;
      const int g8 = col >> 3, c7 = col & 7;
#pragma unroll
      for (int m = 0; m < 4; ++m)
#pragma unroll
        for (int i = 0; i < 4; ++i) {
          const int row = qr[q] + ar0 + m * 16 + ri + i;
          lds[row * 256 + ((g8 ^ (row & 7)) << 3) + c7] =
              f2bf(acc[q][m][n][i] + bv);
        }
    }
  }
  __syncthreads();
#pragma unroll
  for (int jj = 0; jj < 16; ++jj) {
    int c = jj * 512 + tid;
    int row = c >> 5;
    int slot = c & 31;
    u16x8 v = *(const u16x8*)&lds[row * 256 + ((slot ^ (row & 7)) << 3)];
    *(u16x8*)&ob[(size_t)(m0 + row) * ld + ncof + slot * 8] = v;
  }
}

// ============== fused G7 + GRU finish ==============
// A = enhanced [NB,512] bf16; B = 3 gate-strips of w_hh rows
// {j0..j0+127, 512+j0.., 1024+j0..} (384 rows x K). 8 waves (2M x 4J):
// wave owns 64 rows x 32 j x 3 gates -> acc[4][6]. GRU epilogue -> f32 out.
__global__ __launch_bounds__(512, 1) void g7_gru(
    const unsigned short* __restrict__ A, int lda,
    const unsigned short* __restrict__ W, int ldw,
    const float* __restrict__ b_hh, int K, int ntx,
    const unsigned short* __restrict__ gi,
    const unsigned short* __restrict__ enh,
    float* __restrict__ out) {
  __shared__ unsigned short lds[65536];
  unsigned short* Asb = lds;            // [2][8192]  (128 rows x 64)
  unsigned short* Bsb = lds + 16384;    // [2][24576] (384 rows x 64)
  const int tid = threadIdx.x;
  const int lane = tid & 63;
  const int wave = tid >> 6;

  const int nwg = gridDim.x;
  const int cpx = nwg >> 3;
  const int bid = blockIdx.x;
  const int id = (bid & 7) * cpx + (bid >> 3);
  const int bx = id % ntx;   // J-tile (0..3)
  const int by = id / ntx;   // M-tile (0..127)

  const int m0 = by * 128;
  const int j0 = bx * 128;
  const int wm = (wave >> 2) * 64;   // 0 or 64
  const int wj = (wave & 3) * 32;    // 0,32,64,96 within 128-j strip

  f32x4 acc[4][6] = {};  // [m][gate*2+jj]

  const int srow = tid >> 3;                 // 0..63
  const int presw = (tid & 7) ^ (srow & 7);
  const unsigned short* Ag = A + (size_t)(m0 + srow) * lda + presw * 8;
  unsigned short* Asd = Asb + tid * 8;
  unsigned short* Bsd = Bsb + tid * 8;

  auto stage = [&](int buf, int k0) {
    gl_lds16(Ag + k0, Asd + buf * 8192);
    gl_lds16(Ag + (size_t)64 * lda + k0, Asd + buf * 8192 + 4096);
#pragma unroll
    for (int l = 0; l < 6; ++l) {
      const int gate = l >> 1;
      const int rr = (l & 1) * 64 + srow;
      gl_lds16(W + (size_t)(gate * 512 + j0 + rr) * ldw + presw * 8 + k0,
               Bsd + buf * 24576 + l * 4096);
    }
  };

  stage(0, 0);
  int cur = 0;
  const int lrow = lane & 15;
  const int kq = (lane >> 4) * 8;
  const int sw = (lrow & 7) << 3;

  for (int k0 = 0; k0 < K; k0 += 64) {
    if (k0 + 64 < K) {
      stage(cur ^ 1, k0 + 64);
      asm volatile("s_waitcnt vmcnt(8)" ::: "memory");
    } else {
      asm volatile("s_waitcnt vmcnt(0)" ::: "memory");
    }
    __builtin_amdgcn_s_barrier();
    const unsigned short* Ab = Asb + cur * 8192;
    const unsigned short* Bb = Bsb + cur * 24576;
    bf16x8 a[4][2], b[6][2];
#pragma unroll
    for (int m = 0; m < 4; ++m)
#pragma unroll
      for (int kk = 0; kk < 2; ++kk)
        a[m][kk] = *(const bf16x8*)&Ab[(wm + m * 16 + lrow) * 64 +
                                       ((kk * 32 + kq) ^ sw)];
#pragma unroll
    for (int f = 0; f < 6; ++f)
#pragma unroll
      for (int kk = 0; kk < 2; ++kk) {
        const int brow = (f >> 1) * 128 + wj + (f & 1) * 16 + lrow;
        b[f][kk] = *(const bf16x8*)&Bb[brow * 64 + ((kk * 32 + kq) ^ sw)];
      }
    __builtin_amdgcn_s_setprio(1);
#pragma unroll
    for (int m = 0; m < 4; ++m)
#pragma unroll
      for (int f = 0; f < 6; ++f)
#pragma unroll
        for (int kk = 0; kk < 2; ++kk)
          acc[m][f] = __builtin_amdgcn_mfma_f32_16x16x32_bf16(a[m][kk], b[f][kk],
                                                              acc[m][f], 0, 0, 0);
    __builtin_amdgcn_s_setprio(0);
    __builtin_amdgcn_s_barrier();
    cur ^= 1;
  }

  // GRU epilogue: r = sig(gi_r + h_r), z = sig(gi_z + h_z),
  // n = tanh(gi_n + r*h_n), out = (1-z)*n + z*enh.
  const int r0 = m0 + wm + ((lane >> 4) << 2);
#pragma unroll
  for (int jj = 0; jj < 2; ++jj) {
    const int j = j0 + wj + jj * 16 + lrow;   // gate-col in [0,512)
    const float bhr = b_hh[j];
    const float bhz = b_hh[512 + j];
    const float bhn = b_hh[1024 + j];
#pragma unroll
    for (int m = 0; m < 4; ++m) {
#pragma unroll
      for (int i = 0; i < 4; ++i) {
        const int row = r0 + m * 16 + i;
        const size_t gb = (size_t)row * 1536 + j;
        float ir = bf2f(gi[gb]);
        float iz = bf2f(gi[gb + 512]);
        float in_ = bf2f(gi[gb + 1024]);
        float hr = acc[m][jj][i] + bhr;
        float hz = acc[m][2 + jj][i] + bhz;
        float hn = acc[m][4 + jj][i] + bhn;
        float rr = sigmoidf_(ir + hr);
        float zz = sigmoidf_(iz + hz);
        float nn = tanhf(in_ + rr * hn);
        float ev = bf2f(enh[(size_t)row * 512 + j]);
        out[(size_t)row * 512 + j] = (1.0f - zz) * nn + zz * ev;
      }
    }
  }
}

// ============== 128x128 GEMM (small grids: G4, G5) — R6-proven ==============
template <int EPI>
__global__ __launch_bounds__(256, 2) void gemm_bt(
    const unsigned short* __restrict__ A, int lda,
    const unsigned short* __restrict__ W, int ldw,
    const float* __restrict__ bias, int K, int ntx,
    unsigned short* __restrict__ outb, int ldob,
    const unsigned short* __restrict__ gin) {
  __shared__ unsigned short As[2][128 * 64];
  __shared__ unsigned short Ws[2][128 * 64];
  const int tid = threadIdx.x;
  const int lane = tid & 63;
  const int wave = tid >> 6;

  const int nwg = gridDim.x;
  const int cpx = nwg >> 3;
  const int bid = blockIdx.x;
  const int id = (bid & 7) * cpx + (bid >> 3);
  const int bx = id % ntx;
  const int by = id / ntx;

  const int m0 = by * 128;
  const int n0 = bx * 128;
  const int wm = (wave >> 1) * 64;
  const int wn = (wave & 1) * 64;

  f32x4 acc[4][4] = {};

  const int srow = tid >> 3;
  const int sslot = (tid & 7) ^ (srow & 7);
  const unsigned short* Ag = A + (size_t)(m0 + srow) * lda + sslot * 8;
  const unsigned short* Wg = W + (size_t)(n0 + srow) * ldw + sslot * 8;
  unsigned short* Asd = &As[0][tid * 8];
  unsigned short* Wsd = &Ws[0][tid * 8];

  auto stage = [&](int buf, int k0) {
#pragma unroll
    for (int i = 0; i < 4; ++i) {
      gl_lds16(Ag + (size_t)(i * 32) * lda + k0, Asd + buf * 8192 + i * 2048);
      gl_lds16(Wg + (size_t)(i * 32) * ldw + k0, Wsd + buf * 8192 + i * 2048);
    }
  };

  stage(0, 0);
  int cur = 0;
  const int lrow = lane & 15;
  const int kq = (lane >> 4) * 8;
  const int sw = (lrow & 7) << 3;

  for (int k0 = 0; k0 < K; k0 += 64) {
    if (k0 + 64 < K) {
      stage(cur ^ 1, k0 + 64);
      asm volatile("s_waitcnt vmcnt(8)" ::: "memory");
    } else {
      asm volatile("s_waitcnt vmcnt(0)" ::: "memory");
    }
    __builtin_amdgcn_s_barrier();
#pragma unroll
    for (int kk = 0; kk < 2; ++kk) {
      const int kr = kk * 32 + kq;
      const int ki = kr ^ sw;
      bf16x8 af[4], wf[4];
#pragma unroll
      for (int m = 0; m < 4; ++m)
        af[m] = *(const bf16x8*)&As[cur][(wm + m * 16 + lrow) * 64 + ki];
#pragma unroll
      for (int n = 0; n < 4; ++n)
        wf[n] = *(const bf16x8*)&Ws[cur][(wn + n * 16 + lrow) * 64 + ki];
#pragma unroll
      for (int m = 0; m < 4; ++m)
#pragma unroll
        for (int n = 0; n < 4; ++n)
          acc[m][n] = __builtin_amdgcn_mfma_f32_16x16x32_bf16(af[m], wf[n],
                                                              acc[m][n], 0, 0, 0);
    }
    __builtin_amdgcn_s_barrier();
    cur ^= 1;
  }

  if constexpr (EPI == 1) {
    // gate epilogue: g = sigmoid(acc + bias); enhanced = hp + g*sc  (bf16 gin)
    const int r0 = m0 + wm + ((lane >> 4) << 2);
    const int c0 = n0 + wn + lrow;
#pragma unroll
    for (int n = 0; n < 4; ++n) {
      const int col = c0 + n * 16;
      const float bv = bias ? bias[col] : 0.0f;
#pragma unroll
      for (int m = 0; m < 4; ++m) {
#pragma unroll
        for (int i = 0; i < 4; ++i) {
          const int row = r0 + m * 16 + i;
          float g = sigmoidf_(acc[m][n][i] + bv);
          float hpv = bf2f(gin[(size_t)row * 1536 + col]);
          float sc = bf2f(gin[(size_t)row * 1536 + 512 + col]);
          float e = hpv + g * sc;
          outb[(size_t)row * 512 + col] = f2bf(e);
        }
      }
    }
  } else {
    unsigned short* Cs = &As[0][0];
    const int r0l = wm + ((lane >> 4) << 2);
    const int c0l = wn + lrow;
#pragma unroll
    for (int n = 0; n < 4; ++n) {
      const int col = c0l + n * 16;
      const float bv = bias ? bias[n0 + col] : 0.0f;
#pragma unroll
      for (int m = 0; m < 4; ++m)
#pragma unroll
        for (int i = 0; i < 4; ++i)
          Cs[(r0l + m * 16 + i) * 128 + col] = f2bf(acc[m][n][i] + bv);
    }
    __syncthreads();
#pragma unroll
    for (int jj = 0; jj < 8; ++jj) {
      int c = jj * 256 + tid;
      int row = c >> 4;
      int slot = c & 15;
      u16x8 v = *(const u16x8*)&Cs[row * 128 + slot * 8];
      *(u16x8*)&outb[(size_t)(m0 + row) * ldob + n0 + slot * 8] = v;
    }
  }
}

// ---------------- attention over the 2 neighbor states ----------------
__global__ void attn_fuse(const unsigned short* __restrict__ qkvl,
                          const unsigned short* __restrict__ qkvu,
                          unsigned short* __restrict__ ctx) {
  int t = blockIdx.x * blockDim.x + threadIdx.x;
  int g = t >> 4;
  int l = t & 15;
  int b = g >> 2, h = g & 3;
  const size_t base = (size_t)b * 1536 + h * 128 + l * 8;
  u16x8 q0 = *(const u16x8*)(qkvl + base);
  u16x8 k0 = *(const u16x8*)(qkvl + base + 512);
  u16x8 v0 = *(const u16x8*)(qkvl + base + 1024);
  u16x8 q1 = *(const u16x8*)(qkvu + base);
  u16x8 k1 = *(const u16x8*)(qkvu + base + 512);
  u16x8 v1 = *(const u16x8*)(qkvu + base + 1024);
  float s00 = 0.f, s01 = 0.f, s10 = 0.f, s11 = 0.f;
  float v0f[8], v1f[8];
#pragma unroll
  for (int i = 0; i < 8; ++i) {
    float q0f = bf2f(q0[i]), q1f = bf2f(q1[i]);
    float k0f = bf2f(k0[i]), k1f = bf2f(k1[i]);
    v0f[i] = bf2f(v0[i]); v1f[i] = bf2f(v1[i]);
    s00 += q0f * k0f; s01 += q0f * k1f;
    s10 += q1f * k0f; s11 += q1f * k1f;
  }
#pragma unroll
  for (int off = 1; off < 16; off <<= 1) {
    s00 += __shfl_xor(s00, off);
    s01 += __shfl_xor(s01, off);
    s10 += __shfl_xor(s10, off);
    s11 += __shfl_xor(s11, off);
  }
  const float scale = 0.0883883476483184f;
  s00 *= scale; s01 *= scale; s10 *= scale; s11 *= scale;
  float m0 = fmaxf(s00, s01), m1 = fmaxf(s10, s11);
  float a00 = __expf(s00 - m0), a01 = __expf(s01 - m0);
  float a10 = __expf(s10 - m1), a11 = __expf(s11 - m1);
  float c0 = 0.5f * (a00 / (a00 + a01) + a10 / (a10 + a11));
  float c1 = 0.5f * (a01 / (a00 + a01) + a11 / (a10 + a11));
  u16x8 o;
#pragma unroll
  for (int i = 0; i < 8; ++i) o[i] = f2bf(c0 * v0f[i] + c1 * v1f[i]);
  *(u16x8*)(ctx + (size_t)b * 512 + h * 128 + l * 8) = o;
}

extern "C" void kernel_launch(void* const* d_in, const int* in_sizes, int n_in,
                              void* d_out, int out_size, void* d_ws, size_t ws_size,
                              hipStream_t stream) {
  const float* x = (const float*)d_in[0];
  const float* hl = (const float*)d_in[1];
  const float* hu = (const float*)d_in[2];
  const float* hp = (const float*)d_in[3];
  const float* W_in = (const float*)d_in[4];
  const float* b_in = (const float*)d_in[5];
  const float* attn_in_w = (const float*)d_in[6];
  const float* attn_in_b = (const float*)d_in[7];
  const float* attn_out_w = (const float*)d_in[8];
  const float* attn_out_b = (const float*)d_in[9];
  const float* W_gate = (const float*)d_in[10];
  const float* b_gate = (const float*)d_in[11];
  const float* gru_w_ih = (const float*)d_in[12];
  const float* gru_w_hh = (const float*)d_in[13];
  const float* gru_b_ih = (const float*)d_in[14];
  const float* gru_b_hh = (const float*)d_in[15];

  char* ws = (char*)d_ws;
  size_t off = 0;
  auto alloc = [&](size_t bytes) {
    void* p = ws + off;
    off += (bytes + 255) & ~(size_t)255;
    return p;
  };
  unsigned short* wComb = (unsigned short*)alloc((size_t)2048 * 128 * 2);
  unsigned short* wAin  = (unsigned short*)alloc((size_t)1536 * 512 * 2);
  unsigned short* wAout = (unsigned short*)alloc((size_t)512 * 512 * 2);
  unsigned short* wGate = (unsigned short*)alloc((size_t)512 * 1536 * 2);
  unsigned short* wHh   = (unsigned short*)alloc((size_t)1536 * 512 * 2);
  unsigned short* xb   = (unsigned short*)alloc((size_t)NB * 128 * 2);
  unsigned short* hlub = (unsigned short*)alloc((size_t)2 * NB * 512 * 2);
  unsigned short* gate_in = (unsigned short*)alloc((size_t)NB * 1536 * 2);
  unsigned short* qkvb = (unsigned short*)alloc((size_t)2 * NB * 1536 * 2);
  unsigned short* ctxb = (unsigned short*)alloc((size_t)NB * 512 * 2);
  unsigned short* enhb = (unsigned short*)alloc((size_t)NB * 512 * 2);
  unsigned short* qkvl = qkvb;
  unsigned short* qkvu = qkvb + (size_t)NB * 1536;
  unsigned short* gi = qkvl;

  (void)ws_size; (void)in_sizes; (void)n_in; (void)out_size;

  const int T = 256;

  CvtJobs jobs;
  jobs.src[0] = W_in;       jobs.dst[0] = wComb;
  jobs.src[1] = gru_w_ih;   jobs.dst[1] = wComb + (size_t)512 * 128;
  jobs.src[2] = attn_in_w;  jobs.dst[2] = wAin;
  jobs.src[3] = attn_out_w; jobs.dst[3] = wAout;
  jobs.src[4] = W_gate;     jobs.dst[4] = wGate;
  jobs.src[5] = gru_w_hh;   jobs.dst[5] = wHh;
  jobs.src[6] = x;          jobs.dst[6] = xb;
  jobs.src[7] = hl;         jobs.dst[7] = hlub;
  jobs.src[8] = hu;         jobs.dst[8] = hlub + (size_t)NB * 512;
  cvt_multi<<<(CT + T - 1) / T, T, 0, stream>>>(jobs);
  pack_hp<<<NB * 64 / T, T, 0, stream>>>(hp, gate_in);

  const int MTB = NB / 256;
  const int MTS = NB / 128;

  // G2 batched: qkv for [hl;hu]
  gemm_big<0><<<6 * 2 * MTB, dim3(512), 0, stream>>>(hlub, 512, wAin, 512,
                                                     attn_in_b, nullptr, 512, 6,
                                                     qkvb, 1536, nullptr, 0);
  attn_fuse<<<NB * NHEADS * 16 / T, T, 0, stream>>>(qkvl, qkvu, ctxb);
  // G4
  gemm_bt<0><<<4 * MTS, T, 0, stream>>>(ctxb, 512, wAout, 512, attn_out_b,
                                        512, 4,
                                        gate_in + 512, 1536, nullptr);
  // G1+G6 fused
  gemm_big<2><<<8 * MTB, dim3(512), 0, stream>>>(xb, 128, wComb, 128,
                                                 b_in, gru_b_ih, 128, 8,
                                                 gate_in + 1024, 1536, gi, 1536);
  // G5: gate + enhanced (hp/sc from gate_in bf16; writes enhb only)
  gemm_bt<1><<<4 * MTS, T, 0, stream>>>(gate_in, 1536, wGate, 1536, b_gate,
                                        1536, 4,
                                        enhb, 512, gate_in);
  // G7 + GRU fused: 128 M-tiles x 4 J-tiles = 512 blocks (2 exact rounds)
  g7_gru<<<4 * MTS, dim3(512), 0, stream>>>(enhb, 512, wHh, 512, gru_b_hh,
                                            512, 4, gi, enhb, (float*)d_out);
}

// Round 13
// 236.251 us; speedup vs baseline: 1.7317x; 1.1475x over previous
//
#include <hip/hip_runtime.h>
#include <hip/hip_bf16.h>
#include <stdint.h>

// ImprovedLatticeRNNCell, round 13.
// R12 + fused qkv+attention ("qkva"): A = row-interleaved [hl;hu] (row 2b=hl_b,
// 2b+1=hu_b); B = q,k,v 128-row strips of one head (g7_gru 3-strip staging);
// attention computed in-epilogue from a padded LDS tile; ctx written directly.
// attn_fuse and pack_hp kernels eliminated (pack_hp folded into cvt job 9).

#define NB 16384

typedef __attribute__((ext_vector_type(8))) __bf16 bf16x8;
typedef __attribute__((ext_vector_type(4))) float f32x4;
typedef __attribute__((ext_vector_type(8))) unsigned short u16x8;

__device__ __forceinline__ unsigned short f2bf(float f) {
  union { float f; unsigned int u; } v; v.f = f;
  unsigned int u = v.u;
  unsigned int r = (u + 0x7fffu + ((u >> 16) & 1u)) >> 16;
  return (unsigned short)r;
}
__device__ __forceinline__ float bf2f(unsigned short h) {
  union { unsigned int u; float f; } v; v.u = ((unsigned int)h) << 16;
  return v.f;
}
__device__ __forceinline__ float sigmoidf_(float x) {
  return 1.0f / (1.0f + __expf(-x));
}

// ------------- merged f32 -> bf16 conversion (10 jobs, 1 launch) ------------
// jobs 7/8 write row-interleaved into hlib; job 9 writes hp strided into
// gate_in (cols 0..511 of 1536-wide rows).
#define J0 (512 * 128 / 8)
#define J1 (1536 * 128 / 8)
#define J2 (1536 * 512 / 8)
#define J3 (512 * 512 / 8)
#define J4 (512 * 1536 / 8)
#define J5 (1536 * 512 / 8)
#define J6 (NB * 128 / 8)
#define J7 (NB * 512 / 8)
#define J8 (NB * 512 / 8)
#define J9 (NB * 512 / 8)
#define C1 (J0)
#define C2 (C1 + J1)
#define C3 (C2 + J2)
#define C4 (C3 + J3)
#define C5 (C4 + J4)
#define C6 (C5 + J5)
#define C7 (C6 + J6)
#define C8 (C7 + J7)
#define C9 (C8 + J8)
#define CT (C9 + J9)

struct CvtJobs {
  const float* src[10];
  unsigned short* dst[10];
};

__global__ void cvt_multi(CvtJobs j) {
  int g = blockIdx.x * blockDim.x + threadIdx.x;
  if (g >= CT) return;
  int k, base;
  if (g < C4) {
    if (g < C2) {
      if (g < C1) { k = 0; base = 0; } else { k = 1; base = C1; }
    } else {
      if (g < C3) { k = 2; base = C2; } else { k = 3; base = C3; }
    }
  } else {
    if (g < C6) {
      if (g < C5) { k = 4; base = C4; } else { k = 5; base = C5; }
    } else {
      if (g < C7) { k = 6; base = C6; }
      else if (g < C8) { k = 7; base = C7; }
      else if (g < C9) { k = 8; base = C8; }
      else { k = 9; base = C9; }
    }
  }
  int local = g - base;
  const float4* s = (const float4*)j.src[k] + (size_t)local * 2;
  float4 a = s[0], b = s[1];
  u16x8 o;
  o[0] = f2bf(a.x); o[1] = f2bf(a.y); o[2] = f2bf(a.z); o[3] = f2bf(a.w);
  o[4] = f2bf(b.x); o[5] = f2bf(b.y); o[6] = f2bf(b.z); o[7] = f2bf(b.w);
  size_t didx;
  if (k == 7)      didx = ((size_t)(local >> 6) << 7) + (local & 63);        // row 2b
  else if (k == 8) didx = ((size_t)(local >> 6) << 7) + 64 + (local & 63);   // row 2b+1
  else if (k == 9) didx = (size_t)(local >> 6) * 192 + (local & 63);         // gate_in stride
  else             didx = (size_t)local;
  *((u16x8*)j.dst[k] + didx) = o;
}

__device__ __forceinline__ void gl_lds16(const unsigned short* g, unsigned short* l) {
  __builtin_amdgcn_global_load_lds(
      (const __attribute__((address_space(1))) void*)g,
      (__attribute__((address_space(3))) void*)l, 16, 0, 0);
}

// ============== 256x256 GEMM, 4-phase quadrant schedule (R10-proven) =========
template <int EPI>
__global__ __launch_bounds__(512, 1) void gemm_big(
    const unsigned short* __restrict__ A, int lda,
    const unsigned short* __restrict__ W, int ldw,
    const float* __restrict__ bias, const float* __restrict__ bias2,
    int K, int ntx,
    unsigned short* __restrict__ outb, int ldob,
    unsigned short* __restrict__ outb2, int ldob2) {
  __shared__ unsigned short lds[65536];
  unsigned short* Asb = lds;
  unsigned short* Bsb = lds + 32768;
  const int tid = threadIdx.x;
  const int lane = tid & 63;
  const int wave = tid >> 6;

  const int nwg = gridDim.x;
  const int cpx = nwg >> 3;
  const int bid = blockIdx.x;
  const int id = (bid & 7) * cpx + (bid >> 3);
  const int bx = id % ntx;
  const int by = id / ntx;

  const int m0 = by * 256;
  const int n0 = bx * 256;
  const int ar0 = (wave >> 2) * 64;
  const int br0 = (wave & 3) * 32;

  f32x4 acc[4][4][2] = {};

  const int srow = tid >> 3;
  const int presw = (tid & 7) ^ (srow & 7);
  const unsigned short* Ag = A + (size_t)(m0 + srow) * lda + presw * 8;
  const unsigned short* Wg = W + (size_t)(n0 + srow) * ldw + presw * 8;
  unsigned short* Asd = Asb + tid * 8;
  unsigned short* Wsd = Bsb + tid * 8;

  auto stageA = [&](int buf, int h, int k0) {
    const unsigned short* s = Ag + (size_t)(h * 128) * lda + k0;
    unsigned short* d = Asd + buf * 16384 + h * 8192;
    gl_lds16(s, d);
    gl_lds16(s + (size_t)64 * lda, d + 4096);
  };
  auto stageB = [&](int buf, int h, int k0) {
    const unsigned short* s = Wg + (size_t)(h * 128) * ldw + k0;
    unsigned short* d = Wsd + buf * 16384 + h * 8192;
    gl_lds16(s, d);
    gl_lds16(s + (size_t)64 * ldw, d + 4096);
  };

  const int lrow = lane & 15;
  const int kq = (lane >> 4) * 8;
  const int sw = (lrow & 7) << 3;
  const int NT = K >> 6;

  stageA(0, 0, 0);
  stageB(0, 0, 0);
  stageB(0, 1, 0);
  stageA(0, 1, 0);
  asm volatile("s_waitcnt vmcnt(4)" ::: "memory");
  __builtin_amdgcn_s_barrier();

  bf16x8 a[4][2], b0[2][2], b1[2][2];

#define RD_A(X, H)                                                            \
  _Pragma("unroll") for (int m = 0; m < 4; ++m)                               \
  _Pragma("unroll") for (int kk = 0; kk < 2; ++kk)                            \
      a[m][kk] = *(const bf16x8*)&Asb[(X) * 16384 +                           \
                                      ((H) * 128 + ar0 + m * 16 + lrow) * 64 +\
                                      ((kk * 32 + kq) ^ sw)];
#define RD_B(X, H, DST)                                                       \
  _Pragma("unroll") for (int n = 0; n < 2; ++n)                               \
  _Pragma("unroll") for (int kk = 0; kk < 2; ++kk)                            \
      DST[n][kk] = *(const bf16x8*)&Bsb[(X) * 16384 +                         \
                                        ((H) * 128 + br0 + n * 16 + lrow) * 64 + \
                                        ((kk * 32 + kq) ^ sw)];
#define MFMA_Q(Q, BF)                                                         \
  __builtin_amdgcn_s_setprio(1);                                              \
  _Pragma("unroll") for (int m = 0; m < 4; ++m)                               \
  _Pragma("unroll") for (int n = 0; n < 2; ++n)                               \
  _Pragma("unroll") for (int kk = 0; kk < 2; ++kk)                            \
      acc[Q][m][n] = __builtin_amdgcn_mfma_f32_16x16x32_bf16(                 \
          a[m][kk], BF[n][kk], acc[Q][m][n], 0, 0, 0);                        \
  __builtin_amdgcn_s_setprio(0);
#define LGKM0                                                                 \
  asm volatile("s_waitcnt lgkmcnt(0)" ::: "memory");                          \
  __builtin_amdgcn_sched_barrier(0);
#define BAR __builtin_amdgcn_s_barrier();

  for (int t = 0; t < NT - 1; ++t) {
    const int X = t & 1, Y = X ^ 1;
    const int kn = (t + 1) << 6;
    RD_A(X, 0)
    RD_B(X, 0, b0)
    stageA(Y, 0, kn);
    stageB(Y, 0, kn);
    asm volatile("s_waitcnt vmcnt(4)" ::: "memory");
    BAR LGKM0
    MFMA_Q(0, b0)
    BAR
    RD_B(X, 1, b1)
    stageB(Y, 1, kn);
    BAR LGKM0
    MFMA_Q(1, b1)
    BAR
    RD_A(X, 1)
    stageA(Y, 1, kn);
    BAR LGKM0
    MFMA_Q(2, b1)
    BAR
    asm volatile("s_waitcnt vmcnt(4)" ::: "memory");
    BAR
    __builtin_amdgcn_sched_barrier(0);
    MFMA_Q(3, b0)
    BAR
  }
  {
    const int X = (NT - 1) & 1;
    RD_A(X, 0)
    RD_B(X, 0, b0)
    asm volatile("s_waitcnt vmcnt(0)" ::: "memory");
    BAR LGKM0
    MFMA_Q(0, b0)
    RD_B(X, 1, b1)
    LGKM0
    MFMA_Q(1, b1)
    RD_A(X, 1)
    LGKM0
    MFMA_Q(2, b1)
    MFMA_Q(3, b0)
  }
#undef RD_A
#undef RD_B
#undef MFMA_Q
#undef LGKM0
#undef BAR

  __syncthreads();
  unsigned short* ob = outb;
  int ld = ldob, ncof = n0;
  const float* bp = bias;
  if constexpr (EPI == 2) {
    if (n0 >= 512) { ob = outb2; ld = ldob2; ncof = n0 - 512; bp = bias2; }
  }
  const int qr[4] = {0, 0, 128, 128};
  const int qc[4] = {0, 128, 128, 0};
  const int ri = (lane >> 4) << 2;
#pragma unroll
  for (int q = 0; q < 4; ++q) {
#pragma unroll
    for (int n = 0; n < 2; ++n) {
      const int col = qc[q] + br0 + n * 16 + lrow;
      const float bv = bp ? bp[ncof + col] : 0.0f;
      const int g8 = col >> 3, c7 = col & 7;
#pragma unroll
      for (int m = 0; m < 4; ++m)
#pragma unroll
        for (int i = 0; i < 4; ++i) {
          const int row = qr[q] + ar0 + m * 16 + ri + i;
          lds[row * 256 + ((g8 ^ (row & 7)) << 3) + c7] =
              f2bf(acc[q][m][n][i] + bv);
        }
    }
  }
  __syncthreads();
#pragma unroll
  for (int jj = 0; jj < 16; ++jj) {
    int c = jj * 512 + tid;
    int row = c >> 5;
    int slot = c & 31;
    u16x8 v = *(const u16x8*)&lds[row * 256 + ((slot ^ (row & 7)) << 3)];
    *(u16x8*)&ob[(size_t)(m0 + row) * ld + ncof + slot * 8] = v;
  }
}

// ============== fused qkv + attention ("qkva") ==============
// A = hlib [2*NB, 512] row-interleaved (2b=hl_b, 2b+1=hu_b).
// B = q,k,v 128-row strips of head h from attn_in_w (g7_gru 3-strip staging).
// Epilogue: q,k,v -> padded LDS tile -> per-pair attention -> ctx [NB,512].
__global__ __launch_bounds__(512, 1) void qkva(
    const unsigned short* __restrict__ A,
    const unsigned short* __restrict__ W,
    const float* __restrict__ bias,
    unsigned short* __restrict__ ctx) {
  __shared__ unsigned short lds[65536];
  unsigned short* Asb = lds;            // [2][8192]
  unsigned short* Bsb = lds + 16384;    // [2][24576]
  const int tid = threadIdx.x;
  const int lane = tid & 63;
  const int wave = tid >> 6;

  const int nwg = gridDim.x;   // 1024
  const int cpx = nwg >> 3;
  const int bid = blockIdx.x;
  const int id = (bid & 7) * cpx + (bid >> 3);
  const int bx = id & 3;       // head
  const int by = id >> 2;      // M-tile 0..255

  const int m0 = by * 128;     // interleaved row base
  const int h0 = bx * 128;     // head col base within each gate block
  const int wm = (wave >> 2) * 64;
  const int wj = (wave & 3) * 32;

  f32x4 acc[4][6] = {};

  const int srow = tid >> 3;
  const int presw = (tid & 7) ^ (srow & 7);
  const unsigned short* Ag = A + (size_t)(m0 + srow) * 512 + presw * 8;
  unsigned short* Asd = Asb + tid * 8;
  unsigned short* Bsd = Bsb + tid * 8;

  auto stage = [&](int buf, int k0) {
    gl_lds16(Ag + k0, Asd + buf * 8192);
    gl_lds16(Ag + (size_t)64 * 512 + k0, Asd + buf * 8192 + 4096);
#pragma unroll
    for (int l = 0; l < 6; ++l) {
      const int gate = l >> 1;
      const int rr = (l & 1) * 64 + srow;
      gl_lds16(W + (size_t)(gate * 512 + h0 + rr) * 512 + presw * 8 + k0,
               Bsd + buf * 24576 + l * 4096);
    }
  };

  stage(0, 0);
  int cur = 0;
  const int lrow = lane & 15;
  const int kq = (lane >> 4) * 8;
  const int sw = (lrow & 7) << 3;

  for (int k0 = 0; k0 < 512; k0 += 64) {
    if (k0 + 64 < 512) {
      stage(cur ^ 1, k0 + 64);
      asm volatile("s_waitcnt vmcnt(8)" ::: "memory");
    } else {
      asm volatile("s_waitcnt vmcnt(0)" ::: "memory");
    }
    __builtin_amdgcn_s_barrier();
    const unsigned short* Ab = Asb + cur * 8192;
    const unsigned short* Bb = Bsb + cur * 24576;
    bf16x8 a[4][2], b[6][2];
#pragma unroll
    for (int m = 0; m < 4; ++m)
#pragma unroll
      for (int kk = 0; kk < 2; ++kk)
        a[m][kk] = *(const bf16x8*)&Ab[(wm + m * 16 + lrow) * 64 +
                                       ((kk * 32 + kq) ^ sw)];
#pragma unroll
    for (int f = 0; f < 6; ++f)
#pragma unroll
      for (int kk = 0; kk < 2; ++kk) {
        const int brow = (f >> 1) * 128 + wj + (f & 1) * 16 + lrow;
        b[f][kk] = *(const bf16x8*)&Bb[brow * 64 + ((kk * 32 + kq) ^ sw)];
      }
    __builtin_amdgcn_s_setprio(1);
#pragma unroll
    for (int m = 0; m < 4; ++m)
#pragma unroll
      for (int f = 0; f < 6; ++f)
#pragma unroll
        for (int kk = 0; kk < 2; ++kk)
          acc[m][f] = __builtin_amdgcn_mfma_f32_16x16x32_bf16(a[m][kk], b[f][kk],
                                                              acc[m][f], 0, 0, 0);
    __builtin_amdgcn_s_setprio(0);
    __builtin_amdgcn_s_barrier();
    cur ^= 1;
  }

  // --- epilogue: q,k,v -> padded LDS tiles [128][136] per gate ---
  __syncthreads();
  const int ri = (lane >> 4) << 2;
#pragma unroll
  for (int f = 0; f < 6; ++f) {
    const int gate = f >> 1;
    const int col = wj + (f & 1) * 16 + lrow;
    const float bv = bias[gate * 512 + h0 + col];
#pragma unroll
    for (int m = 0; m < 4; ++m)
#pragma unroll
      for (int i = 0; i < 4; ++i) {
        const int row = wm + m * 16 + ri + i;
        lds[gate * 17408 + row * 136 + col] = f2bf(acc[m][f][i] + bv);
      }
  }
  __syncthreads();

  // --- attention: 64 pairs; 16 lanes per pair; 2 iterations ---
  const int l = tid & 15;
  const int grp = tid >> 4;  // 0..31
#pragma unroll
  for (int it = 0; it < 2; ++it) {
    const int p = it * 32 + grp;
    const int r0 = 2 * p, r1 = 2 * p + 1;
    u16x8 q0 = *(const u16x8*)&lds[r0 * 136 + l * 8];
    u16x8 q1 = *(const u16x8*)&lds[r1 * 136 + l * 8];
    u16x8 k0 = *(const u16x8*)&lds[17408 + r0 * 136 + l * 8];
    u16x8 k1 = *(const u16x8*)&lds[17408 + r1 * 136 + l * 8];
    u16x8 v0 = *(const u16x8*)&lds[34816 + r0 * 136 + l * 8];
    u16x8 v1 = *(const u16x8*)&lds[34816 + r1 * 136 + l * 8];
    float s00 = 0.f, s01 = 0.f, s10 = 0.f, s11 = 0.f;
    float v0f[8], v1f[8];
#pragma unroll
    for (int i = 0; i < 8; ++i) {
      float q0f = bf2f(q0[i]), q1f = bf2f(q1[i]);
      float k0f = bf2f(k0[i]), k1f = bf2f(k1[i]);
      v0f[i] = bf2f(v0[i]); v1f[i] = bf2f(v1[i]);
      s00 += q0f * k0f; s01 += q0f * k1f;
      s10 += q1f * k0f; s11 += q1f * k1f;
    }
#pragma unroll
    for (int off = 1; off < 16; off <<= 1) {
      s00 += __shfl_xor(s00, off);
      s01 += __shfl_xor(s01, off);
      s10 += __shfl_xor(s10, off);
      s11 += __shfl_xor(s11, off);
    }
    const float scale = 0.0883883476483184f;  // 1/sqrt(128)
    s00 *= scale; s01 *= scale; s10 *= scale; s11 *= scale;
    float mx0 = fmaxf(s00, s01), mx1 = fmaxf(s10, s11);
    float a00 = __expf(s00 - mx0), a01 = __expf(s01 - mx0);
    float a10 = __expf(s10 - mx1), a11 = __expf(s11 - mx1);
    float c0 = 0.5f * (a00 / (a00 + a01) + a10 / (a10 + a11));
    float c1 = 0.5f * (a01 / (a00 + a01) + a11 / (a10 + a11));
    u16x8 o;
#pragma unroll
    for (int i = 0; i < 8; ++i) o[i] = f2bf(c0 * v0f[i] + c1 * v1f[i]);
    const int bglob = (m0 >> 1) + p;
    *(u16x8*)&ctx[(size_t)bglob * 512 + h0 + l * 8] = o;
  }
}

// ============== fused G7 + GRU finish (R12-proven) ==============
__global__ __launch_bounds__(512, 1) void g7_gru(
    const unsigned short* __restrict__ A, int lda,
    const unsigned short* __restrict__ W, int ldw,
    const float* __restrict__ b_hh, int K, int ntx,
    const unsigned short* __restrict__ gi,
    const unsigned short* __restrict__ enh,
    float* __restrict__ out) {
  __shared__ unsigned short lds[65536];
  unsigned short* Asb = lds;
  unsigned short* Bsb = lds + 16384;
  const int tid = threadIdx.x;
  const int lane = tid & 63;
  const int wave = tid >> 6;

  const int nwg = gridDim.x;
  const int cpx = nwg >> 3;
  const int bid = blockIdx.x;
  const int id = (bid & 7) * cpx + (bid >> 3);
  const int bx = id % ntx;
  const int by = id / ntx;

  const int m0 = by * 128;
  const int j0 = bx * 128;
  const int wm = (wave >> 2) * 64;
  const int wj = (wave & 3) * 32;

  f32x4 acc[4][6] = {};

  const int srow = tid >> 3;
  const int presw = (tid & 7) ^ (srow & 7);
  const unsigned short* Ag = A + (size_t)(m0 + srow) * lda + presw * 8;
  unsigned short* Asd = Asb + tid * 8;
  unsigned short* Bsd = Bsb + tid * 8;

  auto stage = [&](int buf, int k0) {
    gl_lds16(Ag + k0, Asd + buf * 8192);
    gl_lds16(Ag + (size_t)64 * lda + k0, Asd + buf * 8192 + 4096);
#pragma unroll
    for (int l = 0; l < 6; ++l) {
      const int gate = l >> 1;
      const int rr = (l & 1) * 64 + srow;
      gl_lds16(W + (size_t)(gate * 512 + j0 + rr) * ldw + presw * 8 + k0,
               Bsd + buf * 24576 + l * 4096);
    }
  };

  stage(0, 0);
  int cur = 0;
  const int lrow = lane & 15;
  const int kq = (lane >> 4) * 8;
  const int sw = (lrow & 7) << 3;

  for (int k0 = 0; k0 < K; k0 += 64) {
    if (k0 + 64 < K) {
      stage(cur ^ 1, k0 + 64);
      asm volatile("s_waitcnt vmcnt(8)" ::: "memory");
    } else {
      asm volatile("s_waitcnt vmcnt(0)" ::: "memory");
    }
    __builtin_amdgcn_s_barrier();
    const unsigned short* Ab = Asb + cur * 8192;
    const unsigned short* Bb = Bsb + cur * 24576;
    bf16x8 a[4][2], b[6][2];
#pragma unroll
    for (int m = 0; m < 4; ++m)
#pragma unroll
      for (int kk = 0; kk < 2; ++kk)
        a[m][kk] = *(const bf16x8*)&Ab[(wm + m * 16 + lrow) * 64 +
                                       ((kk * 32 + kq) ^ sw)];
#pragma unroll
    for (int f = 0; f < 6; ++f)
#pragma unroll
      for (int kk = 0; kk < 2; ++kk) {
        const int brow = (f >> 1) * 128 + wj + (f & 1) * 16 + lrow;
        b[f][kk] = *(const bf16x8*)&Bb[brow * 64 + ((kk * 32 + kq) ^ sw)];
      }
    __builtin_amdgcn_s_setprio(1);
#pragma unroll
    for (int m = 0; m < 4; ++m)
#pragma unroll
      for (int f = 0; f < 6; ++f)
#pragma unroll
        for (int kk = 0; kk < 2; ++kk)
          acc[m][f] = __builtin_amdgcn_mfma_f32_16x16x32_bf16(a[m][kk], b[f][kk],
                                                              acc[m][f], 0, 0, 0);
    __builtin_amdgcn_s_setprio(0);
    __builtin_amdgcn_s_barrier();
    cur ^= 1;
  }

  const int r0 = m0 + wm + ((lane >> 4) << 2);
#pragma unroll
  for (int jj = 0; jj < 2; ++jj) {
    const int j = j0 + wj + jj * 16 + lrow;
    const float bhr = b_hh[j];
    const float bhz = b_hh[512 + j];
    const float bhn = b_hh[1024 + j];
#pragma unroll
    for (int m = 0; m < 4; ++m) {
#pragma unroll
      for (int i = 0; i < 4; ++i) {
        const int row = r0 + m * 16 + i;
        const size_t gb = (size_t)row * 1536 + j;
        float ir = bf2f(gi[gb]);
        float iz = bf2f(gi[gb + 512]);
        float in_ = bf2f(gi[gb + 1024]);
        float hr = acc[m][jj][i] + bhr;
        float hz = acc[m][2 + jj][i] + bhz;
        float hn = acc[m][4 + jj][i] + bhn;
        float rr = sigmoidf_(ir + hr);
        float zz = sigmoidf_(iz + hz);
        float nn = tanhf(in_ + rr * hn);
        float ev = bf2f(enh[(size_t)row * 512 + j]);
        out[(size_t)row * 512 + j] = (1.0f - zz) * nn + zz * ev;
      }
    }
  }
}

// ============== 128x128 GEMM (small grids: G4, G5) — R6-proven ==============
template <int EPI>
__global__ __launch_bounds__(256, 2) void gemm_bt(
    const unsigned short* __restrict__ A, int lda,
    const unsigned short* __restrict__ W, int ldw,
    const float* __restrict__ bias, int K, int ntx,
    unsigned short* __restrict__ outb, int ldob,
    const unsigned short* __restrict__ gin) {
  __shared__ unsigned short As[2][128 * 64];
  __shared__ unsigned short Ws[2][128 * 64];
  const int tid = threadIdx.x;
  const int lane = tid & 63;
  const int wave = tid >> 6;

  const int nwg = gridDim.x;
  const int cpx = nwg >> 3;
  const int bid = blockIdx.x;
  const int id = (bid & 7) * cpx + (bid >> 3);
  const int bx = id % ntx;
  const int by = id / ntx;

  const int m0 = by * 128;
  const int n0 = bx * 128;
  const int wm = (wave >> 1) * 64;
  const int wn = (wave & 1) * 64;

  f32x4 acc[4][4] = {};

  const int srow = tid >> 3;
  const int sslot = (tid & 7) ^ (srow & 7);
  const unsigned short* Ag = A + (size_t)(m0 + srow) * lda + sslot * 8;
  const unsigned short* Wg = W + (size_t)(n0 + srow) * ldw + sslot * 8;
  unsigned short* Asd = &As[0][tid * 8];
  unsigned short* Wsd = &Ws[0][tid * 8];

  auto stage = [&](int buf, int k0) {
#pragma unroll
    for (int i = 0; i < 4; ++i) {
      gl_lds16(Ag + (size_t)(i * 32) * lda + k0, Asd + buf * 8192 + i * 2048);
      gl_lds16(Wg + (size_t)(i * 32) * ldw + k0, Wsd + buf * 8192 + i * 2048);
    }
  };

  stage(0, 0);
  int cur = 0;
  const int lrow = lane & 15;
  const int kq = (lane >> 4) * 8;
  const int sw = (lrow & 7) << 3;

  for (int k0 = 0; k0 < K; k0 += 64) {
    if (k0 + 64 < K) {
      stage(cur ^ 1, k0 + 64);
      asm volatile("s_waitcnt vmcnt(8)" ::: "memory");
    } else {
      asm volatile("s_waitcnt vmcnt(0)" ::: "memory");
    }
    __builtin_amdgcn_s_barrier();
#pragma unroll
    for (int kk = 0; kk < 2; ++kk) {
      const int kr = kk * 32 + kq;
      const int ki = kr ^ sw;
      bf16x8 af[4], wf[4];
#pragma unroll
      for (int m = 0; m < 4; ++m)
        af[m] = *(const bf16x8*)&As[cur][(wm + m * 16 + lrow) * 64 + ki];
#pragma unroll
      for (int n = 0; n < 4; ++n)
        wf[n] = *(const bf16x8*)&Ws[cur][(wn + n * 16 + lrow) * 64 + ki];
#pragma unroll
      for (int m = 0; m < 4; ++m)
#pragma unroll
        for (int n = 0; n < 4; ++n)
          acc[m][n] = __builtin_amdgcn_mfma_f32_16x16x32_bf16(af[m], wf[n],
                                                              acc[m][n], 0, 0, 0);
    }
    __builtin_amdgcn_s_barrier();
    cur ^= 1;
  }

  if constexpr (EPI == 1) {
    const int r0 = m0 + wm + ((lane >> 4) << 2);
    const int c0 = n0 + wn + lrow;
#pragma unroll
    for (int n = 0; n < 4; ++n) {
      const int col = c0 + n * 16;
      const float bv = bias ? bias[col] : 0.0f;
#pragma unroll
      for (int m = 0; m < 4; ++m) {
#pragma unroll
        for (int i = 0; i < 4; ++i) {
          const int row = r0 + m * 16 + i;
          float g = sigmoidf_(acc[m][n][i] + bv);
          float hpv = bf2f(gin[(size_t)row * 1536 + col]);
          float sc = bf2f(gin[(size_t)row * 1536 + 512 + col]);
          float e = hpv + g * sc;
          outb[(size_t)row * 512 + col] = f2bf(e);
        }
      }
    }
  } else {
    unsigned short* Cs = &As[0][0];
    const int r0l = wm + ((lane >> 4) << 2);
    const int c0l = wn + lrow;
#pragma unroll
    for (int n = 0; n < 4; ++n) {
      const int col = c0l + n * 16;
      const float bv = bias ? bias[n0 + col] : 0.0f;
#pragma unroll
      for (int m = 0; m < 4; ++m)
#pragma unroll
        for (int i = 0; i < 4; ++i)
          Cs[(r0l + m * 16 + i) * 128 + col] = f2bf(acc[m][n][i] + bv);
    }
    __syncthreads();
#pragma unroll
    for (int jj = 0; jj < 8; ++jj) {
      int c = jj * 256 + tid;
      int row = c >> 4;
      int slot = c & 15;
      u16x8 v = *(const u16x8*)&Cs[row * 128 + slot * 8];
      *(u16x8*)&outb[(size_t)(m0 + row) * ldob + n0 + slot * 8] = v;
    }
  }
}

extern "C" void kernel_launch(void* const* d_in, const int* in_sizes, int n_in,
                              void* d_out, int out_size, void* d_ws, size_t ws_size,
                              hipStream_t stream) {
  const float* x = (const float*)d_in[0];
  const float* hl = (const float*)d_in[1];
  const float* hu = (const float*)d_in[2];
  const float* hp = (const float*)d_in[3];
  const float* W_in = (const float*)d_in[4];
  const float* b_in = (const float*)d_in[5];
  const float* attn_in_w = (const float*)d_in[6];
  const float* attn_in_b = (const float*)d_in[7];
  const float* attn_out_w = (const float*)d_in[8];
  const float* attn_out_b = (const float*)d_in[9];
  const float* W_gate = (const float*)d_in[10];
  const float* b_gate = (const float*)d_in[11];
  const float* gru_w_ih = (const float*)d_in[12];
  const float* gru_w_hh = (const float*)d_in[13];
  const float* gru_b_ih = (const float*)d_in[14];
  const float* gru_b_hh = (const float*)d_in[15];

  char* ws = (char*)d_ws;
  size_t off = 0;
  auto alloc = [&](size_t bytes) {
    void* p = ws + off;
    off += (bytes + 255) & ~(size_t)255;
    return p;
  };
  unsigned short* wComb = (unsigned short*)alloc((size_t)2048 * 128 * 2);
  unsigned short* wAin  = (unsigned short*)alloc((size_t)1536 * 512 * 2);
  unsigned short* wAout = (unsigned short*)alloc((size_t)512 * 512 * 2);
  unsigned short* wGate = (unsigned short*)alloc((size_t)512 * 1536 * 2);
  unsigned short* wHh   = (unsigned short*)alloc((size_t)1536 * 512 * 2);
  unsigned short* xb   = (unsigned short*)alloc((size_t)NB * 128 * 2);
  unsigned short* hlib = (unsigned short*)alloc((size_t)2 * NB * 512 * 2);  // interleaved
  unsigned short* gate_in = (unsigned short*)alloc((size_t)NB * 1536 * 2);
  unsigned short* qkvb = (unsigned short*)alloc((size_t)2 * NB * 1536 * 2);
  unsigned short* ctxb = (unsigned short*)alloc((size_t)NB * 512 * 2);
  unsigned short* enhb = (unsigned short*)alloc((size_t)NB * 512 * 2);
  unsigned short* gi = qkvb;

  (void)ws_size; (void)in_sizes; (void)n_in; (void)out_size;

  const int T = 256;

  CvtJobs jobs;
  jobs.src[0] = W_in;       jobs.dst[0] = wComb;
  jobs.src[1] = gru_w_ih;   jobs.dst[1] = wComb + (size_t)512 * 128;
  jobs.src[2] = attn_in_w;  jobs.dst[2] = wAin;
  jobs.src[3] = attn_out_w; jobs.dst[3] = wAout;
  jobs.src[4] = W_gate;     jobs.dst[4] = wGate;
  jobs.src[5] = gru_w_hh;   jobs.dst[5] = wHh;
  jobs.src[6] = x;          jobs.dst[6] = xb;
  jobs.src[7] = hl;         jobs.dst[7] = hlib;   // interleaved even rows
  jobs.src[8] = hu;         jobs.dst[8] = hlib;   // interleaved odd rows
  jobs.src[9] = hp;         jobs.dst[9] = gate_in;  // cols 0..511, stride 1536
  cvt_multi<<<(CT + T - 1) / T, T, 0, stream>>>(jobs);

  const int MTB = NB / 256;
  const int MTS = NB / 128;

  // fused qkv + attention: 256 M-tiles x 4 heads = 1024 blocks
  qkva<<<1024, dim3(512), 0, stream>>>(hlib, wAin, attn_in_b, ctxb);
  // G4: spatial_combined -> gate_in cols 512..1023
  gemm_bt<0><<<4 * MTS, T, 0, stream>>>(ctxb, 512, wAout, 512, attn_out_b,
                                        512, 4,
                                        gate_in + 512, 1536, nullptr);
  // G1+G6 fused
  gemm_big<2><<<8 * MTB, dim3(512), 0, stream>>>(xb, 128, wComb, 128,
                                                 b_in, gru_b_ih, 128, 8,
                                                 gate_in + 1024, 1536, gi, 1536);
  // G5: gate + enhanced
  gemm_bt<1><<<4 * MTS, T, 0, stream>>>(gate_in, 1536, wGate, 1536, b_gate,
                                        1536, 4,
                                        enhb, 512, gate_in);
  // G7 + GRU fused
  g7_gru<<<4 * MTS, dim3(512), 0, stream>>>(enhb, 512, wHh, 512, gru_b_hh,
                                            512, 4, gi, enhb, (float*)d_out);
}

// Round 14
// 220.421 us; speedup vs baseline: 1.8561x; 1.0718x over previous
//
#include <hip/hip_runtime.h>
#include <hip/hip_bf16.h>
#include <stdint.h>

// ImprovedLatticeRNNCell, round 14.
// R13 + vectorized epilogues:
//  - g7_gru: hr/hz/hn staged to LDS bf16 [3][128][136]; GRU pass uses u16x8
//    gi/enh loads + float4 stores (was 128 scalar 2B loads/thread).
//  - gemm_bt EPI1 (G5): g staged to Cs; vectorized hp/sc loads + u16x8 store.

#define NB 16384

typedef __attribute__((ext_vector_type(8))) __bf16 bf16x8;
typedef __attribute__((ext_vector_type(4))) float f32x4;
typedef __attribute__((ext_vector_type(8))) unsigned short u16x8;

__device__ __forceinline__ unsigned short f2bf(float f) {
  union { float f; unsigned int u; } v; v.f = f;
  unsigned int u = v.u;
  unsigned int r = (u + 0x7fffu + ((u >> 16) & 1u)) >> 16;
  return (unsigned short)r;
}
__device__ __forceinline__ float bf2f(unsigned short h) {
  union { unsigned int u; float f; } v; v.u = ((unsigned int)h) << 16;
  return v.f;
}
__device__ __forceinline__ float sigmoidf_(float x) {
  return 1.0f / (1.0f + __expf(-x));
}

// ------------- merged f32 -> bf16 conversion (10 jobs, 1 launch) ------------
#define J0 (512 * 128 / 8)
#define J1 (1536 * 128 / 8)
#define J2 (1536 * 512 / 8)
#define J3 (512 * 512 / 8)
#define J4 (512 * 1536 / 8)
#define J5 (1536 * 512 / 8)
#define J6 (NB * 128 / 8)
#define J7 (NB * 512 / 8)
#define J8 (NB * 512 / 8)
#define J9 (NB * 512 / 8)
#define C1 (J0)
#define C2 (C1 + J1)
#define C3 (C2 + J2)
#define C4 (C3 + J3)
#define C5 (C4 + J4)
#define C6 (C5 + J5)
#define C7 (C6 + J6)
#define C8 (C7 + J7)
#define C9 (C8 + J8)
#define CT (C9 + J9)

struct CvtJobs {
  const float* src[10];
  unsigned short* dst[10];
};

__global__ void cvt_multi(CvtJobs j) {
  int g = blockIdx.x * blockDim.x + threadIdx.x;
  if (g >= CT) return;
  int k, base;
  if (g < C4) {
    if (g < C2) {
      if (g < C1) { k = 0; base = 0; } else { k = 1; base = C1; }
    } else {
      if (g < C3) { k = 2; base = C2; } else { k = 3; base = C3; }
    }
  } else {
    if (g < C6) {
      if (g < C5) { k = 4; base = C4; } else { k = 5; base = C5; }
    } else {
      if (g < C7) { k = 6; base = C6; }
      else if (g < C8) { k = 7; base = C7; }
      else if (g < C9) { k = 8; base = C8; }
      else { k = 9; base = C9; }
    }
  }
  int local = g - base;
  const float4* s = (const float4*)j.src[k] + (size_t)local * 2;
  float4 a = s[0], b = s[1];
  u16x8 o;
  o[0] = f2bf(a.x); o[1] = f2bf(a.y); o[2] = f2bf(a.z); o[3] = f2bf(a.w);
  o[4] = f2bf(b.x); o[5] = f2bf(b.y); o[6] = f2bf(b.z); o[7] = f2bf(b.w);
  size_t didx;
  if (k == 7)      didx = ((size_t)(local >> 6) << 7) + (local & 63);
  else if (k == 8) didx = ((size_t)(local >> 6) << 7) + 64 + (local & 63);
  else if (k == 9) didx = (size_t)(local >> 6) * 192 + (local & 63);
  else             didx = (size_t)local;
  *((u16x8*)j.dst[k] + didx) = o;
}

__device__ __forceinline__ void gl_lds16(const unsigned short* g, unsigned short* l) {
  __builtin_amdgcn_global_load_lds(
      (const __attribute__((address_space(1))) void*)g,
      (__attribute__((address_space(3))) void*)l, 16, 0, 0);
}

// ============== 256x256 GEMM, 4-phase quadrant schedule (R10-proven) =========
template <int EPI>
__global__ __launch_bounds__(512, 1) void gemm_big(
    const unsigned short* __restrict__ A, int lda,
    const unsigned short* __restrict__ W, int ldw,
    const float* __restrict__ bias, const float* __restrict__ bias2,
    int K, int ntx,
    unsigned short* __restrict__ outb, int ldob,
    unsigned short* __restrict__ outb2, int ldob2) {
  __shared__ unsigned short lds[65536];
  unsigned short* Asb = lds;
  unsigned short* Bsb = lds + 32768;
  const int tid = threadIdx.x;
  const int lane = tid & 63;
  const int wave = tid >> 6;

  const int nwg = gridDim.x;
  const int cpx = nwg >> 3;
  const int bid = blockIdx.x;
  const int id = (bid & 7) * cpx + (bid >> 3);
  const int bx = id % ntx;
  const int by = id / ntx;

  const int m0 = by * 256;
  const int n0 = bx * 256;
  const int ar0 = (wave >> 2) * 64;
  const int br0 = (wave & 3) * 32;

  f32x4 acc[4][4][2] = {};

  const int srow = tid >> 3;
  const int presw = (tid & 7) ^ (srow & 7);
  const unsigned short* Ag = A + (size_t)(m0 + srow) * lda + presw * 8;
  const unsigned short* Wg = W + (size_t)(n0 + srow) * ldw + presw * 8;
  unsigned short* Asd = Asb + tid * 8;
  unsigned short* Wsd = Bsb + tid * 8;

  auto stageA = [&](int buf, int h, int k0) {
    const unsigned short* s = Ag + (size_t)(h * 128) * lda + k0;
    unsigned short* d = Asd + buf * 16384 + h * 8192;
    gl_lds16(s, d);
    gl_lds16(s + (size_t)64 * lda, d + 4096);
  };
  auto stageB = [&](int buf, int h, int k0) {
    const unsigned short* s = Wg + (size_t)(h * 128) * ldw + k0;
    unsigned short* d = Wsd + buf * 16384 + h * 8192;
    gl_lds16(s, d);
    gl_lds16(s + (size_t)64 * ldw, d + 4096);
  };

  const int lrow = lane & 15;
  const int kq = (lane >> 4) * 8;
  const int sw = (lrow & 7) << 3;
  const int NT = K >> 6;

  stageA(0, 0, 0);
  stageB(0, 0, 0);
  stageB(0, 1, 0);
  stageA(0, 1, 0);
  asm volatile("s_waitcnt vmcnt(4)" ::: "memory");
  __builtin_amdgcn_s_barrier();

  bf16x8 a[4][2], b0[2][2], b1[2][2];

#define RD_A(X, H)                                                            \
  _Pragma("unroll") for (int m = 0; m < 4; ++m)                               \
  _Pragma("unroll") for (int kk = 0; kk < 2; ++kk)                            \
      a[m][kk] = *(const bf16x8*)&Asb[(X) * 16384 +                           \
                                      ((H) * 128 + ar0 + m * 16 + lrow) * 64 +\
                                      ((kk * 32 + kq) ^ sw)];
#define RD_B(X, H, DST)                                                       \
  _Pragma("unroll") for (int n = 0; n < 2; ++n)                               \
  _Pragma("unroll") for (int kk = 0; kk < 2; ++kk)                            \
      DST[n][kk] = *(const bf16x8*)&Bsb[(X) * 16384 +                         \
                                        ((H) * 128 + br0 + n * 16 + lrow) * 64 + \
                                        ((kk * 32 + kq) ^ sw)];
#define MFMA_Q(Q, BF)                                                         \
  __builtin_amdgcn_s_setprio(1);                                              \
  _Pragma("unroll") for (int m = 0; m < 4; ++m)                               \
  _Pragma("unroll") for (int n = 0; n < 2; ++n)                               \
  _Pragma("unroll") for (int kk = 0; kk < 2; ++kk)                            \
      acc[Q][m][n] = __builtin_amdgcn_mfma_f32_16x16x32_bf16(                 \
          a[m][kk], BF[n][kk], acc[Q][m][n], 0, 0, 0);                        \
  __builtin_amdgcn_s_setprio(0);
#define LGKM0                                                                 \
  asm volatile("s_waitcnt lgkmcnt(0)" ::: "memory");                          \
  __builtin_amdgcn_sched_barrier(0);
#define BAR __builtin_amdgcn_s_barrier();

  for (int t = 0; t < NT - 1; ++t) {
    const int X = t & 1, Y = X ^ 1;
    const int kn = (t + 1) << 6;
    RD_A(X, 0)
    RD_B(X, 0, b0)
    stageA(Y, 0, kn);
    stageB(Y, 0, kn);
    asm volatile("s_waitcnt vmcnt(4)" ::: "memory");
    BAR LGKM0
    MFMA_Q(0, b0)
    BAR
    RD_B(X, 1, b1)
    stageB(Y, 1, kn);
    BAR LGKM0
    MFMA_Q(1, b1)
    BAR
    RD_A(X, 1)
    stageA(Y, 1, kn);
    BAR LGKM0
    MFMA_Q(2, b1)
    BAR
    asm volatile("s_waitcnt vmcnt(4)" ::: "memory");
    BAR
    __builtin_amdgcn_sched_barrier(0);
    MFMA_Q(3, b0)
    BAR
  }
  {
    const int X = (NT - 1) & 1;
    RD_A(X, 0)
    RD_B(X, 0, b0)
    asm volatile("s_waitcnt vmcnt(0)" ::: "memory");
    BAR LGKM0
    MFMA_Q(0, b0)
    RD_B(X, 1, b1)
    LGKM0
    MFMA_Q(1, b1)
    RD_A(X, 1)
    LGKM0
    MFMA_Q(2, b1)
    MFMA_Q(3, b0)
  }
#undef RD_A
#undef RD_B
#undef MFMA_Q
#undef LGKM0
#undef BAR

  __syncthreads();
  unsigned short* ob = outb;
  int ld = ldob, ncof = n0;
  const float* bp = bias;
  if constexpr (EPI == 2) {
    if (n0 >= 512) { ob = outb2; ld = ldob2; ncof = n0 - 512; bp = bias2; }
  }
  const int qr[4] = {0, 0, 128, 128};
  const int qc[4] = {0, 128, 128, 0};
  const int ri = (lane >> 4) << 2;
#pragma unroll
  for (int q = 0; q < 4; ++q) {
#pragma unroll
    for (int n = 0; n < 2; ++n) {
      const int col = qc[q] + br0 + n * 16 + lrow;
      const float bv = bp ? bp[ncof + col] : 0.0f;
      const int g8 = col >> 3, c7 = col & 7;
#pragma unroll
      for (int m = 0; m < 4; ++m)
#pragma unroll
        for (int i = 0; i < 4; ++i) {
          const int row = qr[q] + ar0 + m * 16 + ri + i;
          lds[row * 256 + ((g8 ^ (row & 7)) << 3) + c7] =
              f2bf(acc[q][m][n][i] + bv);
        }
    }
  }
  __syncthreads();
#pragma unroll
  for (int jj = 0; jj < 16; ++jj) {
    int c = jj * 512 + tid;
    int row = c >> 5;
    int slot = c & 31;
    u16x8 v = *(const u16x8*)&lds[row * 256 + ((slot ^ (row & 7)) << 3)];
    *(u16x8*)&ob[(size_t)(m0 + row) * ld + ncof + slot * 8] = v;
  }
}

// ============== fused qkv + attention ("qkva", R13-proven) ==============
__global__ __launch_bounds__(512, 1) void qkva(
    const unsigned short* __restrict__ A,
    const unsigned short* __restrict__ W,
    const float* __restrict__ bias,
    unsigned short* __restrict__ ctx) {
  __shared__ unsigned short lds[65536];
  unsigned short* Asb = lds;
  unsigned short* Bsb = lds + 16384;
  const int tid = threadIdx.x;
  const int lane = tid & 63;
  const int wave = tid >> 6;

  const int nwg = gridDim.x;
  const int cpx = nwg >> 3;
  const int bid = blockIdx.x;
  const int id = (bid & 7) * cpx + (bid >> 3);
  const int bx = id & 3;
  const int by = id >> 2;

  const int m0 = by * 128;
  const int h0 = bx * 128;
  const int wm = (wave >> 2) * 64;
  const int wj = (wave & 3) * 32;

  f32x4 acc[4][6] = {};

  const int srow = tid >> 3;
  const int presw = (tid & 7) ^ (srow & 7);
  const unsigned short* Ag = A + (size_t)(m0 + srow) * 512 + presw * 8;
  unsigned short* Asd = Asb + tid * 8;
  unsigned short* Bsd = Bsb + tid * 8;

  auto stage = [&](int buf, int k0) {
    gl_lds16(Ag + k0, Asd + buf * 8192);
    gl_lds16(Ag + (size_t)64 * 512 + k0, Asd + buf * 8192 + 4096);
#pragma unroll
    for (int l = 0; l < 6; ++l) {
      const int gate = l >> 1;
      const int rr = (l & 1) * 64 + srow;
      gl_lds16(W + (size_t)(gate * 512 + h0 + rr) * 512 + presw * 8 + k0,
               Bsd + buf * 24576 + l * 4096);
    }
  };

  stage(0, 0);
  int cur = 0;
  const int lrow = lane & 15;
  const int kq = (lane >> 4) * 8;
  const int sw = (lrow & 7) << 3;

  for (int k0 = 0; k0 < 512; k0 += 64) {
    if (k0 + 64 < 512) {
      stage(cur ^ 1, k0 + 64);
      asm volatile("s_waitcnt vmcnt(8)" ::: "memory");
    } else {
      asm volatile("s_waitcnt vmcnt(0)" ::: "memory");
    }
    __builtin_amdgcn_s_barrier();
    const unsigned short* Ab = Asb + cur * 8192;
    const unsigned short* Bb = Bsb + cur * 24576;
    bf16x8 a[4][2], b[6][2];
#pragma unroll
    for (int m = 0; m < 4; ++m)
#pragma unroll
      for (int kk = 0; kk < 2; ++kk)
        a[m][kk] = *(const bf16x8*)&Ab[(wm + m * 16 + lrow) * 64 +
                                       ((kk * 32 + kq) ^ sw)];
#pragma unroll
    for (int f = 0; f < 6; ++f)
#pragma unroll
      for (int kk = 0; kk < 2; ++kk) {
        const int brow = (f >> 1) * 128 + wj + (f & 1) * 16 + lrow;
        b[f][kk] = *(const bf16x8*)&Bb[brow * 64 + ((kk * 32 + kq) ^ sw)];
      }
    __builtin_amdgcn_s_setprio(1);
#pragma unroll
    for (int m = 0; m < 4; ++m)
#pragma unroll
      for (int f = 0; f < 6; ++f)
#pragma unroll
        for (int kk = 0; kk < 2; ++kk)
          acc[m][f] = __builtin_amdgcn_mfma_f32_16x16x32_bf16(a[m][kk], b[f][kk],
                                                              acc[m][f], 0, 0, 0);
    __builtin_amdgcn_s_setprio(0);
    __builtin_amdgcn_s_barrier();
    cur ^= 1;
  }

  __syncthreads();
  const int ri = (lane >> 4) << 2;
#pragma unroll
  for (int f = 0; f < 6; ++f) {
    const int gate = f >> 1;
    const int col = wj + (f & 1) * 16 + lrow;
    const float bv = bias[gate * 512 + h0 + col];
#pragma unroll
    for (int m = 0; m < 4; ++m)
#pragma unroll
      for (int i = 0; i < 4; ++i) {
        const int row = wm + m * 16 + ri + i;
        lds[gate * 17408 + row * 136 + col] = f2bf(acc[m][f][i] + bv);
      }
  }
  __syncthreads();

  const int l = tid & 15;
  const int grp = tid >> 4;
#pragma unroll
  for (int it = 0; it < 2; ++it) {
    const int p = it * 32 + grp;
    const int r0 = 2 * p, r1 = 2 * p + 1;
    u16x8 q0 = *(const u16x8*)&lds[r0 * 136 + l * 8];
    u16x8 q1 = *(const u16x8*)&lds[r1 * 136 + l * 8];
    u16x8 k0 = *(const u16x8*)&lds[17408 + r0 * 136 + l * 8];
    u16x8 k1 = *(const u16x8*)&lds[17408 + r1 * 136 + l * 8];
    u16x8 v0 = *(const u16x8*)&lds[34816 + r0 * 136 + l * 8];
    u16x8 v1 = *(const u16x8*)&lds[34816 + r1 * 136 + l * 8];
    float s00 = 0.f, s01 = 0.f, s10 = 0.f, s11 = 0.f;
    float v0f[8], v1f[8];
#pragma unroll
    for (int i = 0; i < 8; ++i) {
      float q0f = bf2f(q0[i]), q1f = bf2f(q1[i]);
      float k0f = bf2f(k0[i]), k1f = bf2f(k1[i]);
      v0f[i] = bf2f(v0[i]); v1f[i] = bf2f(v1[i]);
      s00 += q0f * k0f; s01 += q0f * k1f;
      s10 += q1f * k0f; s11 += q1f * k1f;
    }
#pragma unroll
    for (int off = 1; off < 16; off <<= 1) {
      s00 += __shfl_xor(s00, off);
      s01 += __shfl_xor(s01, off);
      s10 += __shfl_xor(s10, off);
      s11 += __shfl_xor(s11, off);
    }
    const float scale = 0.0883883476483184f;
    s00 *= scale; s01 *= scale; s10 *= scale; s11 *= scale;
    float mx0 = fmaxf(s00, s01), mx1 = fmaxf(s10, s11);
    float a00 = __expf(s00 - mx0), a01 = __expf(s01 - mx0);
    float a10 = __expf(s10 - mx1), a11 = __expf(s11 - mx1);
    float c0 = 0.5f * (a00 / (a00 + a01) + a10 / (a10 + a11));
    float c1 = 0.5f * (a01 / (a00 + a01) + a11 / (a10 + a11));
    u16x8 o;
#pragma unroll
    for (int i = 0; i < 8; ++i) o[i] = f2bf(c0 * v0f[i] + c1 * v1f[i]);
    const int bglob = (m0 >> 1) + p;
    *(u16x8*)&ctx[(size_t)bglob * 512 + h0 + l * 8] = o;
  }
}

// ============== fused G7 + GRU finish (vectorized epilogue) ==============
__global__ __launch_bounds__(512, 1) void g7_gru(
    const unsigned short* __restrict__ A, int lda,
    const unsigned short* __restrict__ W, int ldw,
    const float* __restrict__ b_hh, int K, int ntx,
    const unsigned short* __restrict__ gi,
    const unsigned short* __restrict__ enh,
    float* __restrict__ out) {
  __shared__ unsigned short lds[65536];
  unsigned short* Asb = lds;
  unsigned short* Bsb = lds + 16384;
  const int tid = threadIdx.x;
  const int lane = tid & 63;
  const int wave = tid >> 6;

  const int nwg = gridDim.x;
  const int cpx = nwg >> 3;
  const int bid = blockIdx.x;
  const int id = (bid & 7) * cpx + (bid >> 3);
  const int bx = id % ntx;
  const int by = id / ntx;

  const int m0 = by * 128;
  const int j0 = bx * 128;
  const int wm = (wave >> 2) * 64;
  const int wj = (wave & 3) * 32;

  f32x4 acc[4][6] = {};

  const int srow = tid >> 3;
  const int presw = (tid & 7) ^ (srow & 7);
  const unsigned short* Ag = A + (size_t)(m0 + srow) * lda + presw * 8;
  unsigned short* Asd = Asb + tid * 8;
  unsigned short* Bsd = Bsb + tid * 8;

  auto stage = [&](int buf, int k0) {
    gl_lds16(Ag + k0, Asd + buf * 8192);
    gl_lds16(Ag + (size_t)64 * lda + k0, Asd + buf * 8192 + 4096);
#pragma unroll
    for (int l = 0; l < 6; ++l) {
      const int gate = l >> 1;
      const int rr = (l & 1) * 64 + srow;
      gl_lds16(W + (size_t)(gate * 512 + j0 + rr) * ldw + presw * 8 + k0,
               Bsd + buf * 24576 + l * 4096);
    }
  };

  stage(0, 0);
  int cur = 0;
  const int lrow = lane & 15;
  const int kq = (lane >> 4) * 8;
  const int sw = (lrow & 7) << 3;

  for (int k0 = 0; k0 < K; k0 += 64) {
    if (k0 + 64 < K) {
      stage(cur ^ 1, k0 + 64);
      asm volatile("s_waitcnt vmcnt(8)" ::: "memory");
    } else {
      asm volatile("s_waitcnt vmcnt(0)" ::: "memory");
    }
    __builtin_amdgcn_s_barrier();
    const unsigned short* Ab = Asb + cur * 8192;
    const unsigned short* Bb = Bsb + cur * 24576;
    bf16x8 a[4][2], b[6][2];
#pragma unroll
    for (int m = 0; m < 4; ++m)
#pragma unroll
      for (int kk = 0; kk < 2; ++kk)
        a[m][kk] = *(const bf16x8*)&Ab[(wm + m * 16 + lrow) * 64 +
                                       ((kk * 32 + kq) ^ sw)];
#pragma unroll
    for (int f = 0; f < 6; ++f)
#pragma unroll
      for (int kk = 0; kk < 2; ++kk) {
        const int brow = (f >> 1) * 128 + wj + (f & 1) * 16 + lrow;
        b[f][kk] = *(const bf16x8*)&Bb[brow * 64 + ((kk * 32 + kq) ^ sw)];
      }
    __builtin_amdgcn_s_setprio(1);
#pragma unroll
    for (int m = 0; m < 4; ++m)
#pragma unroll
      for (int f = 0; f < 6; ++f)
#pragma unroll
        for (int kk = 0; kk < 2; ++kk)
          acc[m][f] = __builtin_amdgcn_mfma_f32_16x16x32_bf16(a[m][kk], b[f][kk],
                                                              acc[m][f], 0, 0, 0);
    __builtin_amdgcn_s_setprio(0);
    __builtin_amdgcn_s_barrier();
    cur ^= 1;
  }

  // stage h-gates (+bias) to LDS bf16 [3][128][136]
  __syncthreads();
  const int ri = (lane >> 4) << 2;
#pragma unroll
  for (int f = 0; f < 6; ++f) {
    const int gate = f >> 1;
    const int col = wj + (f & 1) * 16 + lrow;
    const float bh = b_hh[gate * 512 + j0 + col];
#pragma unroll
    for (int m = 0; m < 4; ++m)
#pragma unroll
      for (int i = 0; i < 4; ++i) {
        const int row = wm + m * 16 + ri + i;
        lds[gate * 17408 + row * 136 + col] = f2bf(acc[m][f][i] + bh);
      }
  }
  __syncthreads();

  // vectorized GRU pass: 2048 chunks (128 rows x 16 slots), 4/thread
#pragma unroll
  for (int cc = 0; cc < 4; ++cc) {
    const int c = cc * 512 + tid;
    const int row = c >> 4, slot = c & 15;
    const int rg = m0 + row;
    const int jb = j0 + slot * 8;
    u16x8 hr = *(const u16x8*)&lds[row * 136 + slot * 8];
    u16x8 hz = *(const u16x8*)&lds[17408 + row * 136 + slot * 8];
    u16x8 hn = *(const u16x8*)&lds[34816 + row * 136 + slot * 8];
    const size_t gb = (size_t)rg * 1536 + jb;
    u16x8 ir = *(const u16x8*)&gi[gb];
    u16x8 iz = *(const u16x8*)&gi[gb + 512];
    u16x8 in_ = *(const u16x8*)&gi[gb + 1024];
    u16x8 ev = *(const u16x8*)&enh[(size_t)rg * 512 + jb];
    float of[8];
#pragma unroll
    for (int i = 0; i < 8; ++i) {
      float rr = sigmoidf_(bf2f(ir[i]) + bf2f(hr[i]));
      float zz = sigmoidf_(bf2f(iz[i]) + bf2f(hz[i]));
      float nn = tanhf(bf2f(in_[i]) + rr * bf2f(hn[i]));
      of[i] = (1.0f - zz) * nn + zz * bf2f(ev[i]);
    }
    float* op = out + (size_t)rg * 512 + jb;
    *(float4*)op = make_float4(of[0], of[1], of[2], of[3]);
    *(float4*)(op + 4) = make_float4(of[4], of[5], of[6], of[7]);
  }
}

// ============== 128x128 GEMM (small grids: G4, G5) ==============
template <int EPI>
__global__ __launch_bounds__(256, 2) void gemm_bt(
    const unsigned short* __restrict__ A, int lda,
    const unsigned short* __restrict__ W, int ldw,
    const float* __restrict__ bias, int K, int ntx,
    unsigned short* __restrict__ outb, int ldob,
    const unsigned short* __restrict__ gin) {
  __shared__ unsigned short As[2][128 * 64];
  __shared__ unsigned short Ws[2][128 * 64];
  const int tid = threadIdx.x;
  const int lane = tid & 63;
  const int wave = tid >> 6;

  const int nwg = gridDim.x;
  const int cpx = nwg >> 3;
  const int bid = blockIdx.x;
  const int id = (bid & 7) * cpx + (bid >> 3);
  const int bx = id % ntx;
  const int by = id / ntx;

  const int m0 = by * 128;
  const int n0 = bx * 128;
  const int wm = (wave >> 1) * 64;
  const int wn = (wave & 1) * 64;

  f32x4 acc[4][4] = {};

  const int srow = tid >> 3;
  const int sslot = (tid & 7) ^ (srow & 7);
  const unsigned short* Ag = A + (size_t)(m0 + srow) * lda + sslot * 8;
  const unsigned short* Wg = W + (size_t)(n0 + srow) * ldw + sslot * 8;
  unsigned short* Asd = &As[0][tid * 8];
  unsigned short* Wsd = &Ws[0][tid * 8];

  auto stage = [&](int buf, int k0) {
#pragma unroll
    for (int i = 0; i < 4; ++i) {
      gl_lds16(Ag + (size_t)(i * 32) * lda + k0, Asd + buf * 8192 + i * 2048);
      gl_lds16(Wg + (size_t)(i * 32) * ldw + k0, Wsd + buf * 8192 + i * 2048);
    }
  };

  stage(0, 0);
  int cur = 0;
  const int lrow = lane & 15;
  const int kq = (lane >> 4) * 8;
  const int sw = (lrow & 7) << 3;

  for (int k0 = 0; k0 < K; k0 += 64) {
    if (k0 + 64 < K) {
      stage(cur ^ 1, k0 + 64);
      asm volatile("s_waitcnt vmcnt(8)" ::: "memory");
    } else {
      asm volatile("s_waitcnt vmcnt(0)" ::: "memory");
    }
    __builtin_amdgcn_s_barrier();
#pragma unroll
    for (int kk = 0; kk < 2; ++kk) {
      const int kr = kk * 32 + kq;
      const int ki = kr ^ sw;
      bf16x8 af[4], wf[4];
#pragma unroll
      for (int m = 0; m < 4; ++m)
        af[m] = *(const bf16x8*)&As[cur][(wm + m * 16 + lrow) * 64 + ki];
#pragma unroll
      for (int n = 0; n < 4; ++n)
        wf[n] = *(const bf16x8*)&Ws[cur][(wn + n * 16 + lrow) * 64 + ki];
#pragma unroll
      for (int m = 0; m < 4; ++m)
#pragma unroll
        for (int n = 0; n < 4; ++n)
          acc[m][n] = __builtin_amdgcn_mfma_f32_16x16x32_bf16(af[m], wf[n],
                                                              acc[m][n], 0, 0, 0);
    }
    __builtin_amdgcn_s_barrier();
    cur ^= 1;
  }

  unsigned short* Cs = &As[0][0];  // 128x128 bf16 = 32 KB stage
  const int r0l = wm + ((lane >> 4) << 2);
  const int c0l = wn + lrow;
  if constexpr (EPI == 1) {
    // stage g = sigmoid(acc + bias) as bf16
#pragma unroll
    for (int n = 0; n < 4; ++n) {
      const int col = c0l + n * 16;
      const float bv = bias ? bias[n0 + col] : 0.0f;
#pragma unroll
      for (int m = 0; m < 4; ++m)
#pragma unroll
        for (int i = 0; i < 4; ++i)
          Cs[(r0l + m * 16 + i) * 128 + col] =
              f2bf(sigmoidf_(acc[m][n][i] + bv));
    }
    __syncthreads();
    // vectorized enhanced pass: e = hp + g*sc, 8 chunks/thread
#pragma unroll
    for (int q = 0; q < 8; ++q) {
      const int c = q * 256 + tid;
      const int row = c >> 4, slot = c & 15;
      const int rg = m0 + row;
      const int cb = n0 + slot * 8;
      u16x8 gv = *(const u16x8*)&Cs[row * 128 + slot * 8];
      const size_t rb = (size_t)rg * 1536 + cb;
      u16x8 hpv = *(const u16x8*)&gin[rb];
      u16x8 scv = *(const u16x8*)&gin[rb + 512];
      u16x8 o;
#pragma unroll
      for (int i = 0; i < 8; ++i)
        o[i] = f2bf(bf2f(hpv[i]) + bf2f(gv[i]) * bf2f(scv[i]));
      *(u16x8*)&outb[(size_t)rg * 512 + cb] = o;
    }
  } else {
#pragma unroll
    for (int n = 0; n < 4; ++n) {
      const int col = c0l + n * 16;
      const float bv = bias ? bias[n0 + col] : 0.0f;
#pragma unroll
      for (int m = 0; m < 4; ++m)
#pragma unroll
        for (int i = 0; i < 4; ++i)
          Cs[(r0l + m * 16 + i) * 128 + col] = f2bf(acc[m][n][i] + bv);
    }
    __syncthreads();
#pragma unroll
    for (int jj = 0; jj < 8; ++jj) {
      int c = jj * 256 + tid;
      int row = c >> 4;
      int slot = c & 15;
      u16x8 v = *(const u16x8*)&Cs[row * 128 + slot * 8];
      *(u16x8*)&outb[(size_t)(m0 + row) * ldob + n0 + slot * 8] = v;
    }
  }
}

extern "C" void kernel_launch(void* const* d_in, const int* in_sizes, int n_in,
                              void* d_out, int out_size, void* d_ws, size_t ws_size,
                              hipStream_t stream) {
  const float* x = (const float*)d_in[0];
  const float* hl = (const float*)d_in[1];
  const float* hu = (const float*)d_in[2];
  const float* hp = (const float*)d_in[3];
  const float* W_in = (const float*)d_in[4];
  const float* b_in = (const float*)d_in[5];
  const float* attn_in_w = (const float*)d_in[6];
  const float* attn_in_b = (const float*)d_in[7];
  const float* attn_out_w = (const float*)d_in[8];
  const float* attn_out_b = (const float*)d_in[9];
  const float* W_gate = (const float*)d_in[10];
  const float* b_gate = (const float*)d_in[11];
  const float* gru_w_ih = (const float*)d_in[12];
  const float* gru_w_hh = (const float*)d_in[13];
  const float* gru_b_ih = (const float*)d_in[14];
  const float* gru_b_hh = (const float*)d_in[15];

  char* ws = (char*)d_ws;
  size_t off = 0;
  auto alloc = [&](size_t bytes) {
    void* p = ws + off;
    off += (bytes + 255) & ~(size_t)255;
    return p;
  };
  unsigned short* wComb = (unsigned short*)alloc((size_t)2048 * 128 * 2);
  unsigned short* wAin  = (unsigned short*)alloc((size_t)1536 * 512 * 2);
  unsigned short* wAout = (unsigned short*)alloc((size_t)512 * 512 * 2);
  unsigned short* wGate = (unsigned short*)alloc((size_t)512 * 1536 * 2);
  unsigned short* wHh   = (unsigned short*)alloc((size_t)1536 * 512 * 2);
  unsigned short* xb   = (unsigned short*)alloc((size_t)NB * 128 * 2);
  unsigned short* hlib = (unsigned short*)alloc((size_t)2 * NB * 512 * 2);
  unsigned short* gate_in = (unsigned short*)alloc((size_t)NB * 1536 * 2);
  unsigned short* qkvb = (unsigned short*)alloc((size_t)2 * NB * 1536 * 2);
  unsigned short* ctxb = (unsigned short*)alloc((size_t)NB * 512 * 2);
  unsigned short* enhb = (unsigned short*)alloc((size_t)NB * 512 * 2);
  unsigned short* gi = qkvb;

  (void)ws_size; (void)in_sizes; (void)n_in; (void)out_size;

  const int T = 256;

  CvtJobs jobs;
  jobs.src[0] = W_in;       jobs.dst[0] = wComb;
  jobs.src[1] = gru_w_ih;   jobs.dst[1] = wComb + (size_t)512 * 128;
  jobs.src[2] = attn_in_w;  jobs.dst[2] = wAin;
  jobs.src[3] = attn_out_w; jobs.dst[3] = wAout;
  jobs.src[4] = W_gate;     jobs.dst[4] = wGate;
  jobs.src[5] = gru_w_hh;   jobs.dst[5] = wHh;
  jobs.src[6] = x;          jobs.dst[6] = xb;
  jobs.src[7] = hl;         jobs.dst[7] = hlib;
  jobs.src[8] = hu;         jobs.dst[8] = hlib;
  jobs.src[9] = hp;         jobs.dst[9] = gate_in;
  cvt_multi<<<(CT + T - 1) / T, T, 0, stream>>>(jobs);

  const int MTB = NB / 256;
  const int MTS = NB / 128;

  // fused qkv + attention
  qkva<<<1024, dim3(512), 0, stream>>>(hlib, wAin, attn_in_b, ctxb);
  // G4
  gemm_bt<0><<<4 * MTS, T, 0, stream>>>(ctxb, 512, wAout, 512, attn_out_b,
                                        512, 4,
                                        gate_in + 512, 1536, nullptr);
  // G1+G6 fused
  gemm_big<2><<<8 * MTB, dim3(512), 0, stream>>>(xb, 128, wComb, 128,
                                                 b_in, gru_b_ih, 128, 8,
                                                 gate_in + 1024, 1536, gi, 1536);
  // G5: gate + enhanced (vectorized epilogue)
  gemm_bt<1><<<4 * MTS, T, 0, stream>>>(gate_in, 1536, wGate, 1536, b_gate,
                                        1536, 4,
                                        enhb, 512, gate_in);
  // G7 + GRU fused (vectorized epilogue)
  g7_gru<<<4 * MTS, dim3(512), 0, stream>>>(enhb, 512, wHh, 512, gru_b_hh,
                                            512, 4, gi, enhb, (float*)d_out);
}